// Round 12
// baseline (388.072 us; speedup 1.0000x reference)
//
#include <hip/hip_runtime.h>
#include <math.h>

namespace {

constexpr int Na = 50000, Np = 100000, L = 2, E = 150000;
constexpr int SCAN_TILE = 2048;

typedef __attribute__((ext_vector_type(8))) short short8v;
typedef __attribute__((ext_vector_type(4))) float f32x4;

__device__ inline float geluf(float x){ return 0.5f*x*(1.0f + erff(x*0.7071067811865476f)); }

__device__ inline float bf2f(unsigned short u){ return __uint_as_float(((unsigned)u) << 16); }
__device__ inline unsigned short f2bf(float f){
  unsigned u = __float_as_uint(f);
  u += 0x7FFFu + ((u >> 16) & 1u);   // round-to-nearest-even
  return (unsigned short)(u >> 16);
}
__device__ inline unsigned pk2(float a, float b){
  return (unsigned)f2bf(a) | ((unsigned)f2bf(b) << 16);
}

struct StF32 {
  using T = float;
  static __device__ short8v ld8(const T* __restrict__ p){
    float4 lo = *reinterpret_cast<const float4*>(p);
    float4 hi = *reinterpret_cast<const float4*>(p+4);
    short8v v;
    v[0]=(short)f2bf(lo.x); v[1]=(short)f2bf(lo.y); v[2]=(short)f2bf(lo.z); v[3]=(short)f2bf(lo.w);
    v[4]=(short)f2bf(hi.x); v[5]=(short)f2bf(hi.y); v[6]=(short)f2bf(hi.z); v[7]=(short)f2bf(hi.w);
    return v;
  }
};
struct StBF16 {
  using T = unsigned short;
  static __device__ short8v ld8(const T* __restrict__ p){
    return *reinterpret_cast<const short8v*>(p);
  }
  static __device__ void ld16(const T* __restrict__ p, float* o){
    const uint4* q = reinterpret_cast<const uint4*>(p);
    #pragma unroll
    for (int half = 0; half < 2; ++half){
      uint4 u = q[half];
      o[half*8+0] = bf2f((unsigned short)(u.x & 0xffff));
      o[half*8+1] = bf2f((unsigned short)(u.x >> 16));
      o[half*8+2] = bf2f((unsigned short)(u.y & 0xffff));
      o[half*8+3] = bf2f((unsigned short)(u.y >> 16));
      o[half*8+4] = bf2f((unsigned short)(u.z & 0xffff));
      o[half*8+5] = bf2f((unsigned short)(u.z >> 16));
      o[half*8+6] = bf2f((unsigned short)(u.w & 0xffff));
      o[half*8+7] = bf2f((unsigned short)(u.w >> 16));
    }
  }
};

__global__ void zero_int_kernel(int* __restrict__ p, int n){
  int i = blockIdx.x*256 + threadIdx.x;
  int stride = gridDim.x*256;
  for (; i < n; i += stride) p[i] = 0;
}

__global__ void diag_kernel(float* o, float v){
  if (threadIdx.x == 0 && blockIdx.x == 0) o[0] = v;
}

__global__ void hist_kernel(const int* __restrict__ dst, int* __restrict__ counts, int nE){
  int e = blockIdx.x*256 + threadIdx.x;
  if (e >= nE) return;
  atomicAdd(&counts[dst[e]], 1);
}

// ---- multi-block exclusive scan (3 phases) ----
__global__ void scan_a(const int* __restrict__ counts, int* __restrict__ bsum, int n){
  int base = blockIdx.x*SCAN_TILE;
  int s = 0;
  for (int i = threadIdx.x; i < SCAN_TILE; i += 256){
    int g = base + i;
    s += (g < n) ? counts[g] : 0;
  }
  __shared__ int red[256];
  red[threadIdx.x] = s;
  __syncthreads();
  for (int off = 128; off > 0; off >>= 1){
    if (threadIdx.x < off) red[threadIdx.x] += red[threadIdx.x + off];
    __syncthreads();
  }
  if (threadIdx.x == 0) bsum[blockIdx.x] = red[0];
}

__global__ void scan_b(int* __restrict__ bsum, int nb){
  __shared__ int sh[1024];
  int t = threadIdx.x;
  int v = (t < nb) ? bsum[t] : 0;
  sh[t] = v;
  __syncthreads();
  for (int off = 1; off < 1024; off <<= 1){
    int add = (t >= off) ? sh[t-off] : 0;
    __syncthreads();
    sh[t] += add;
    __syncthreads();
  }
  if (t < nb) bsum[t] = sh[t] - v;   // exclusive
}

__global__ void scan_c(int* __restrict__ counts, const int* __restrict__ bsum,
                       int* __restrict__ rp, int n){
  int base = blockIdx.x*SCAN_TILE;
  __shared__ int sh[SCAN_TILE];
  for (int i = threadIdx.x; i < SCAN_TILE; i += 256){
    int g = base + i;
    sh[i] = (g < n) ? counts[g] : 0;
  }
  __syncthreads();
  int t = threadIdx.x;
  int loc[8], s = 0;
  #pragma unroll
  for (int i = 0; i < 8; ++i){ loc[i] = s; s += sh[t*8 + i]; }
  __shared__ int red[256];
  red[t] = s;
  __syncthreads();
  for (int off = 1; off < 256; off <<= 1){
    int add = (t >= off) ? red[t-off] : 0;
    __syncthreads();
    red[t] += add;
    __syncthreads();
  }
  int texcl = red[t] - s + bsum[blockIdx.x];
  #pragma unroll
  for (int i = 0; i < 8; ++i){
    int g = base + t*8 + i;
    if (g < n){
      int v = texcl + loc[i];
      rp[g] = v;
      counts[g] = v;           // cursor for fill pass
      if (g == n-1) rp[n] = v + sh[t*8 + i];
    }
  }
}

__global__ void fill_slots_kernel(const int* __restrict__ src, const int* __restrict__ dst,
                                  int* __restrict__ cursor, int* __restrict__ slots, int nE){
  int e = blockIdx.x*256 + threadIdx.x;
  if (e >= nE) return;
  int slot = atomicAdd(&cursor[dst[e]], 1);
  slots[slot] = src[e];
}

// Fold rel_a/rel_m into K/V projection weights (fp32).
__global__ void eff_w_kernel(const float* __restrict__ kqv_w, const float* __restrict__ kqv_b,
                             const float* __restrict__ rel_a, const float* __restrict__ rel_m,
                             float* __restrict__ effw, float* __restrict__ effb){
  int idx = blockIdx.x*256 + threadIdx.x;
  if (idx >= 2*2*2*128*128) return;
  int j = idx & 127; int f = (idx >> 7) & 127; int c = idx >> 14;
  int kv = c & 1, t = (c >> 1) & 1, l = c >> 2;
  int h = j >> 4, e2 = j & 15;
  int i = (kv == 0) ? 0 : 2;  // K uses i=0, V uses i=2
  const float* W = kqv_w + ((size_t)(((l*2 + t)*3 + i)*128) + f)*128 + h*16;
  const float* A = ((kv == 0) ? rel_a : rel_m) + ((size_t)(l*2 + t)*8 + h)*256;
  float acc = 0.f;
  #pragma unroll
  for (int d = 0; d < 16; ++d) acc += W[d]*A[d*16 + e2];
  effw[(size_t)c*16384 + f*128 + j] = acc;
  if (f == 0){
    const float* B = kqv_b + (size_t)((l*2 + t)*3 + i)*128 + h*16;
    float ab = 0.f;
    #pragma unroll
    for (int d = 0; d < 16; ++d) ab += B[d]*A[d*16 + e2];
    effb[c*128 + j] = ab;
  }
}

// Convert 19 weight matrices fp32 [k][n] -> bf16 transposed [n][128(k)].
struct PrepSrc { const float* s[19]; };
__global__ void prep_w_kernel(PrepSrc P, unsigned short* __restrict__ wbf){
  int idx = blockIdx.x*256 + threadIdx.x;
  if (idx >= 19*16384) return;
  int s = idx >> 14, j = idx & 16383;
  int n = j >> 7, k = j & 127;
  int nc = (s == 18) ? 64 : 128;
  if (n >= nc) return;
  wbf[(size_t)s*16384 + n*128 + k] = f2bf(P.s[s][(size_t)k*nc + n]);
}

// Stage bf16 WT [rows][128] into LDS with 16B-chunk XOR swizzle (512-thread).
__device__ inline void stage_w(short* Bs, const unsigned short* __restrict__ WT, int t, int rows){
  for (int c = t; c < rows*16; c += 512){
    int r = c >> 4, c16 = c & 15;
    short8v v = *reinterpret_cast<const short8v*>(&WT[r*128 + c16*8]);
    *reinterpret_cast<short8v*>(&Bs[r*128 + ((c16 ^ (r&7))<<3)]) = v;
  }
}

struct GemmArgs {
  const void* X[2];
  const unsigned short* WT[2];
  const float* bias[2];
  void* Y[2];
  const unsigned short* skip_x[2];
  const float* skip_s[2];
  int N[2];
  int blocks0;
};

// MFMA GEMM (512 threads, 8 waves 2x4): Y[N,BN] = epi( X[N,128] @ W + bias ).
// Swapped-operand MFMA -> lane holds 4 consecutive output cols; repack via LDS -> 16B stores.
template<int BN, int RELU_OUT, int SKIP, typename SIn>
__global__ __launch_bounds__(512) void gemm_kernel(GemmArgs Ar)
{
  __shared__ __align__(16) short As[128*128];
  __shared__ __align__(16) char Braw[32768];
  short* Bs = (short*)Braw;
  const int t = threadIdx.x;
  const int part = (blockIdx.x < Ar.blocks0) ? 0 : 1;
  const int bid = part ? (blockIdx.x - Ar.blocks0) : blockIdx.x;
  const typename SIn::T* X = (const typename SIn::T*)Ar.X[part];
  const unsigned short* WT = Ar.WT[part];
  const float* bias = Ar.bias[part];
  const int N = Ar.N[part];
  const int row0 = bid*128;
  for (int c = t; c < 2048; c += 512){
    int r = c >> 4, c16 = c & 15;
    int gr = row0 + r;
    short8v v = (gr < N) ? SIn::ld8(&X[(size_t)gr*128 + c16*8]) : (short8v)0;
    *reinterpret_cast<short8v*>(&As[r*128 + ((c16 ^ (r&7))<<3)]) = v;
  }
  stage_w(Bs, WT, t, BN);
  __syncthreads();
  const int lane = t & 63, wid = t >> 6;
  const int wm = wid >> 2, wn = wid & 3;       // 2 x 4 waves
  constexpr int NR = BN/64;
  const int lr = lane & 15, lk = lane >> 4;
  f32x4 acc[4][NR] = {};
  #pragma unroll
  for (int kk = 0; kk < 4; ++kk){
    int kc = kk*4 + lk;
    short8v a[4], b[NR];
    #pragma unroll
    for (int m = 0; m < 4; ++m){
      int r = wm*64 + m*16 + lr;
      a[m] = *reinterpret_cast<const short8v*>(&As[r*128 + ((kc ^ (r&7))<<3)]);
    }
    #pragma unroll
    for (int n = 0; n < NR; ++n){
      int col = wn*(BN/4) + n*16 + lr;
      b[n] = *reinterpret_cast<const short8v*>(&Bs[col*128 + ((kc ^ (col&7))<<3)]);
    }
    #pragma unroll
    for (int m = 0; m < 4; ++m)
      #pragma unroll
      for (int n = 0; n < NR; ++n)
        acc[m][n] = __builtin_amdgcn_mfma_f32_16x16x32_bf16(b[n], a[m], acc[m][n], 0, 0, 0);
  }
  __syncthreads();   // Bs weight reads done -> reuse as repack buffer

  if constexpr (BN == 128){
    #pragma unroll
    for (int m = 0; m < 4; ++m){
      int row = wm*64 + m*16 + lr;
      #pragma unroll
      for (int n = 0; n < NR; ++n){
        int col0 = wn*32 + n*16 + lk*4;
        float4 b4 = *reinterpret_cast<const float4*>(&bias[col0]);
        float y0 = acc[m][n][0] + b4.x, y1 = acc[m][n][1] + b4.y;
        float y2 = acc[m][n][2] + b4.z, y3 = acc[m][n][3] + b4.w;
        if (RELU_OUT){
          y0 = fmaxf(y0,0.f); y1 = fmaxf(y1,0.f); y2 = fmaxf(y2,0.f); y3 = fmaxf(y3,0.f);
        }
        uint2 pk; pk.x = pk2(y0,y1); pk.y = pk2(y2,y3);
        int c16 = col0 >> 3;
        *reinterpret_cast<uint2*>(&Bs[row*128 + ((c16 ^ (row&7))<<3) + (col0&7)]) = pk;
      }
    }
    __syncthreads();
    float g = 1.f, og = 0.f;
    if (SKIP){ float sv = *Ar.skip_s[part]; g = 1.f/(1.f + expf(-sv)); og = 1.f - g; }
    unsigned short* out = (unsigned short*)Ar.Y[part];
    const unsigned short* skip_x = Ar.skip_x[part];
    for (int c = t; c < 2048; c += 512){
      int r = c >> 4, c16 = c & 15;
      int gr = row0 + r;
      if (gr >= N) continue;
      short8v v = *reinterpret_cast<const short8v*>(&Bs[r*128 + ((c16 ^ (r&7))<<3)]);
      if (SKIP){
        short8v s8 = *reinterpret_cast<const short8v*>(&skip_x[(size_t)gr*128 + c16*8]);
        short8v o8;
        #pragma unroll
        for (int i = 0; i < 8; ++i)
          o8[i] = (short)f2bf(g*bf2f((unsigned short)v[i]) + og*bf2f((unsigned short)s8[i]));
        *reinterpret_cast<short8v*>(&out[(size_t)gr*128 + c16*8]) = o8;
      } else {
        *reinterpret_cast<short8v*>(&out[(size_t)gr*128 + c16*8]) = v;
      }
    }
  } else {
    // BN==64: fp32 repack (32 KB), fp32 coalesced out (classifier)
    float* Bf = (float*)Braw;
    #pragma unroll
    for (int m = 0; m < 4; ++m){
      int row = wm*64 + m*16 + lr;
      int col0 = wn*16 + lk*4;
      float4 b4 = *reinterpret_cast<const float4*>(&bias[col0]);
      float4 y;
      y.x = acc[m][0][0] + b4.x; y.y = acc[m][0][1] + b4.y;
      y.z = acc[m][0][2] + b4.z; y.w = acc[m][0][3] + b4.w;
      int cf = col0 >> 2;
      *reinterpret_cast<float4*>(&Bf[row*64 + ((cf ^ (row&7))<<2)]) = y;
    }
    __syncthreads();
    float* out = (float*)Ar.Y[part];
    for (int c = t; c < 2048; c += 512){
      int r = c >> 4, cf = c & 15;
      int gr = row0 + r;
      if (gr >= N) continue;
      float4 v = *reinterpret_cast<const float4*>(&Bf[r*64 + ((cf ^ (r&7))<<2)]);
      *reinterpret_cast<float4*>(&out[(size_t)gr*64 + cf*4]) = v;
    }
  }
}

struct QkvArgs {
  const unsigned short* X[2];
  const unsigned short* WT[2][3];
  const float* bias[2][3];
  unsigned short* out[2][3];   // [Q, KV, KV]
  int N[2];
  int blocks0;
};

// Fused QKV (512 threads): stage X once; per weight: stage B, MFMA (swapped), repack, store.
// K (s=1) and V (s=2) are written interleaved into the KV buffer: [node][h][K 16 | V 16].
__global__ __launch_bounds__(512) void qkv_kernel(QkvArgs Ar)
{
  __shared__ __align__(16) short As[128*128];
  __shared__ __align__(16) short Bs[128*128];
  const int t = threadIdx.x;
  const int part = (blockIdx.x < Ar.blocks0) ? 0 : 1;
  const int bid = part ? (blockIdx.x - Ar.blocks0) : blockIdx.x;
  const unsigned short* X = Ar.X[part];
  const int N = Ar.N[part];
  const int row0 = bid*128;
  for (int c = t; c < 2048; c += 512){
    int r = c >> 4, c16 = c & 15;
    int gr = row0 + r;
    short8v v = (gr < N) ? *reinterpret_cast<const short8v*>(&X[(size_t)gr*128 + c16*8])
                         : (short8v)0;
    *reinterpret_cast<short8v*>(&As[r*128 + ((c16 ^ (r&7))<<3)]) = v;
  }
  const int lane = t & 63, wid = t >> 6;
  const int wm = wid >> 2, wn = wid & 3;
  const int lr = lane & 15, lk = lane >> 4;
  #pragma unroll
  for (int s = 0; s < 3; ++s){
    __syncthreads();                   // A staged (s=0) / prev readout done
    stage_w(Bs, Ar.WT[part][s], t, 128);
    __syncthreads();
    f32x4 acc[4][2] = {};
    #pragma unroll
    for (int kk = 0; kk < 4; ++kk){
      int kc = kk*4 + lk;
      short8v a[4], b[2];
      #pragma unroll
      for (int m = 0; m < 4; ++m){
        int r = wm*64 + m*16 + lr;
        a[m] = *reinterpret_cast<const short8v*>(&As[r*128 + ((kc ^ (r&7))<<3)]);
      }
      #pragma unroll
      for (int n = 0; n < 2; ++n){
        int col = wn*32 + n*16 + lr;
        b[n] = *reinterpret_cast<const short8v*>(&Bs[col*128 + ((kc ^ (col&7))<<3)]);
      }
      #pragma unroll
      for (int m = 0; m < 4; ++m)
        #pragma unroll
        for (int n = 0; n < 2; ++n)
          acc[m][n] = __builtin_amdgcn_mfma_f32_16x16x32_bf16(b[n], a[m], acc[m][n], 0, 0, 0);
    }
    __syncthreads();                   // weight reads done -> repack into Bs
    const float* bi = Ar.bias[part][s];
    #pragma unroll
    for (int m = 0; m < 4; ++m){
      int row = wm*64 + m*16 + lr;
      #pragma unroll
      for (int n = 0; n < 2; ++n){
        int col0 = wn*32 + n*16 + lk*4;
        float4 b4 = *reinterpret_cast<const float4*>(&bi[col0]);
        uint2 pk;
        pk.x = pk2(acc[m][n][0] + b4.x, acc[m][n][1] + b4.y);
        pk.y = pk2(acc[m][n][2] + b4.z, acc[m][n][3] + b4.w);
        int c16 = col0 >> 3;
        *reinterpret_cast<uint2*>(&Bs[row*128 + ((c16 ^ (row&7))<<3) + (col0&7)]) = pk;
      }
    }
    __syncthreads();
    unsigned short* out = Ar.out[part][s];
    for (int c = t; c < 2048; c += 512){
      int r = c >> 4, c16 = c & 15;
      int gr = row0 + r;
      if (gr >= N) continue;
      short8v v = *reinterpret_cast<const short8v*>(&Bs[r*128 + ((c16 ^ (r&7))<<3)]);
      if (s == 0){
        *reinterpret_cast<short8v*>(&out[(size_t)gr*128 + c16*8]) = v;
      } else {
        // chunk c16 covers cols [c16*8, c16*8+8) = head h=c16>>1, half i0=(c16&1)*8
        // KV chunk index = h*4 + (c16&1) + (s==2 ? 2 : 0); row stride 256
        int kc16 = ((c16 >> 1) << 2) | (c16 & 1) | ((s == 2) ? 2 : 0);
        *reinterpret_cast<short8v*>(&out[(size_t)gr*256 + kc16*8]) = v;
      }
    }
  }
}

struct AttnArgs {
  unsigned short* QA[2];
  const unsigned short* KV[2];
  const int* rp[2];
  const int* slots[2];
  const float* relp[2];
  int N[2];
  int blocks0;
};

// Fused attention (both directions, one launch): thread per (dst node, head).
// KV interleaved: one 64B contiguous read per edge. Edge loop unrolled x2 for MLP.
// Applies gelu to the aggregate before store (a_lin reads pre-activated input).
__global__ void attn_gather_kernel(AttnArgs Ar){
  const int part = (blockIdx.x < Ar.blocks0) ? 0 : 1;
  const int bid = part ? (blockIdx.x - Ar.blocks0) : blockIdx.x;
  int idx = bid*256 + threadIdx.x;
  const int N = Ar.N[part];
  if (idx >= N*8) return;
  int h = idx & 7, n = idx >> 3;
  unsigned short* QA = Ar.QA[part];
  const unsigned short* KV = Ar.KV[part];
  float q[16];
  StBF16::ld16(&QA[(size_t)n*128 + h*16], q);
  float scale_h = Ar.relp[part][h]*0.25f;
  float m = -INFINITY, s = 0.f, acc[16];
  #pragma unroll
  for (int i = 0; i < 16; ++i) acc[i] = 0.f;
  int b = Ar.rp[part][n], e = Ar.rp[part][n+1];
  const int* slots = Ar.slots[part];
  int j = b;
  for (; j + 2 <= e; j += 2){
    int sv0 = slots[j], sv1 = slots[j+1];
    const unsigned short* p0 = KV + (size_t)sv0*256 + h*32;
    const unsigned short* p1 = KV + (size_t)sv1*256 + h*32;
    float kf0[16], vf0[16], kf1[16], vf1[16];
    StBF16::ld16(p0, kf0); StBF16::ld16(p0+16, vf0);
    StBF16::ld16(p1, kf1); StBF16::ld16(p1+16, vf1);
    float a0 = 0.f, a1 = 0.f;
    #pragma unroll
    for (int i = 0; i < 16; ++i){ a0 += q[i]*kf0[i]; a1 += q[i]*kf1[i]; }
    a0 *= scale_h; a1 *= scale_h;
    float mn = fmaxf(m, a0);
    float c = expf(m - mn), p = expf(a0 - mn);
    s = s*c + p;
    #pragma unroll
    for (int i = 0; i < 16; ++i) acc[i] = acc[i]*c + p*vf0[i];
    m = mn;
    mn = fmaxf(m, a1);
    c = expf(m - mn); p = expf(a1 - mn);
    s = s*c + p;
    #pragma unroll
    for (int i = 0; i < 16; ++i) acc[i] = acc[i]*c + p*vf1[i];
    m = mn;
  }
  if (j < e){
    int sv = slots[j];
    const unsigned short* p0 = KV + (size_t)sv*256 + h*32;
    float kf[16], vf[16];
    StBF16::ld16(p0, kf); StBF16::ld16(p0+16, vf);
    float a = 0.f;
    #pragma unroll
    for (int i = 0; i < 16; ++i) a += q[i]*kf[i];
    a *= scale_h;
    float mn = fmaxf(m, a);
    float c = expf(m - mn), p = expf(a - mn);
    s = s*c + p;
    #pragma unroll
    for (int i = 0; i < 16; ++i) acc[i] = acc[i]*c + p*vf[i];
    m = mn;
  }
  float inv = 1.f/(s + 1e-16f);
  #pragma unroll
  for (int i = 0; i < 16; ++i)
    QA[(size_t)n*128 + h*16 + i] = f2bf(geluf(acc[i]*inv));
}

struct Ptrs {
  const float *x_author, *x_paper, *win_w, *win_b, *kqv_w, *kqv_b, *a_w, *a_b;
  const float *skip, *rel_a, *rel_m, *rel_p, *out_w, *out_b;
  const int *src0, *dst0, *src1, *dst1;
};

static void run_pipeline(const Ptrs& P, float* d_out, char* ws, hipStream_t stream){
  using BF = unsigned short;
  size_t off = 0;
  auto alloc = [&](size_t bytes) -> void* {
    void* p = ws + off;
    off += (bytes + 255) & ~(size_t)255;
    return p;
  };
  BF* X0 = (BF*)alloc((size_t)Na*128*2);
  BF* X1 = (BF*)alloc((size_t)Np*128*2);
  BF* Q0 = (BF*)alloc((size_t)Na*128*2);    // Q -> agg in place
  BF* Q1 = (BF*)alloc((size_t)Np*128*2);
  BF* KV0 = (BF*)alloc((size_t)Na*256*2);   // interleaved K|V per head
  BF* KV1 = (BF*)alloc((size_t)Np*256*2);
  float* effw = (float*)alloc((size_t)8*16384*4);
  float* effb = (float*)alloc((size_t)8*128*4);
  BF* wbf = (BF*)alloc((size_t)19*16384*2);
  int* rp0   = (int*)alloc((size_t)(Np+1)*4);
  int* cur0  = (int*)alloc((size_t)Np*4);
  int* slot0 = (int*)alloc((size_t)E*4);
  int* rp1   = (int*)alloc((size_t)(Na+1)*4);
  int* cur1  = (int*)alloc((size_t)Na*4);
  int* slot1 = (int*)alloc((size_t)E*4);
  int* bsum  = (int*)alloc((size_t)1024*4);

  auto cdiv = [](int a, int b){ return (a+b-1)/b; };
  const int geE = cdiv(E, 256);
  const int ga = cdiv(Na, 128), gp = cdiv(Np, 128);
  const int sb0 = cdiv(Np, SCAN_TILE), sb1 = cdiv(Na, SCAN_TILE);

  eff_w_kernel<<<512, 256, 0, stream>>>(P.kqv_w, P.kqv_b, P.rel_a, P.rel_m, effw, effb);

  // weight prep: slots 0-1 win, 2-5 Q(l,t), 6-9 K, 10-13 V, 14-17 a_w, 18 out_w
  PrepSrc ps;
  ps.s[0] = P.win_w; ps.s[1] = P.win_w + 16384;
  for (int l = 0; l < 2; ++l)
    for (int t = 0; t < 2; ++t){
      ps.s[2 + l*2 + t]  = P.kqv_w + (size_t)((l*2+t)*3+1)*16384;
      ps.s[6 + l*2 + t]  = effw + (size_t)(l*4+t*2+0)*16384;
      ps.s[10 + l*2 + t] = effw + (size_t)(l*4+t*2+1)*16384;
      ps.s[14 + l*2 + t] = P.a_w + (size_t)(l*2+t)*16384;
    }
  ps.s[18] = P.out_w;
  prep_w_kernel<<<cdiv(19*16384,256),256,0,stream>>>(ps, wbf);

  // ---- CSR build ----
  zero_int_kernel<<<512,256,0,stream>>>(cur0, Np);
  zero_int_kernel<<<512,256,0,stream>>>(cur1, Na);
  hist_kernel<<<geE,256,0,stream>>>(P.dst0, cur0, E);
  hist_kernel<<<geE,256,0,stream>>>(P.dst1, cur1, E);
  scan_a<<<sb0,256,0,stream>>>(cur0, bsum, Np);
  scan_b<<<1,1024,0,stream>>>(bsum, sb0);
  scan_c<<<sb0,256,0,stream>>>(cur0, bsum, rp0, Np);
  scan_a<<<sb1,256,0,stream>>>(cur1, bsum, Na);
  scan_b<<<1,1024,0,stream>>>(bsum, sb1);
  scan_c<<<sb1,256,0,stream>>>(cur1, bsum, rp1, Na);
  fill_slots_kernel<<<geE,256,0,stream>>>(P.src0, P.dst0, cur0, slot0, E);
  fill_slots_kernel<<<geE,256,0,stream>>>(P.src1, P.dst1, cur1, slot1, E);

  auto W = [&](int s){ return wbf + (size_t)s*16384; };

  // input projections + relu (fp32 in, bf16 out) — merged pair
  {
    GemmArgs g{};
    g.X[0] = P.x_author; g.X[1] = P.x_paper;
    g.WT[0] = W(0); g.WT[1] = W(1);
    g.bias[0] = P.win_b; g.bias[1] = P.win_b + 128;
    g.Y[0] = X0; g.Y[1] = X1;
    g.N[0] = Na; g.N[1] = Np; g.blocks0 = ga;
    gemm_kernel<128,1,0,StF32><<<ga+gp,512,0,stream>>>(g);
  }

  const int ab0 = cdiv(Np*8,256), ab1 = cdiv(Na*8,256);

  for (int l = 0; l < L; ++l){
    QkvArgs q{};
    q.X[0] = X0; q.X[1] = X1;
    for (int t2 = 0; t2 < 2; ++t2){
      q.WT[t2][0] = W(2+l*2+t2); q.WT[t2][1] = W(6+l*2+t2); q.WT[t2][2] = W(10+l*2+t2);
      q.bias[t2][0] = P.kqv_b + ((l*2+t2)*3+1)*128;
      q.bias[t2][1] = effb + (l*4+t2*2+0)*128;
      q.bias[t2][2] = effb + (l*4+t2*2+1)*128;
    }
    q.out[0][0] = Q0; q.out[0][1] = KV0; q.out[0][2] = KV0;
    q.out[1][0] = Q1; q.out[1][1] = KV1; q.out[1][2] = KV1;
    q.N[0] = Na; q.N[1] = Np; q.blocks0 = ga;
    qkv_kernel<<<ga+gp,512,0,stream>>>(q);

    AttnArgs a{};
    a.QA[0] = Q1; a.KV[0] = KV0; a.rp[0] = rp0; a.slots[0] = slot0;
    a.relp[0] = P.rel_p + (l*2+0)*8; a.N[0] = Np;
    a.QA[1] = Q0; a.KV[1] = KV1; a.rp[1] = rp1; a.slots[1] = slot1;
    a.relp[1] = P.rel_p + (l*2+1)*8; a.N[1] = Na;
    a.blocks0 = ab0;
    attn_gather_kernel<<<ab0+ab1,256,0,stream>>>(a);

    GemmArgs g{};
    g.X[0] = Q0; g.X[1] = Q1;
    g.WT[0] = W(14+l*2+0); g.WT[1] = W(14+l*2+1);
    g.bias[0] = P.a_b + (l*2+0)*128; g.bias[1] = P.a_b + (l*2+1)*128;
    g.Y[0] = X0; g.Y[1] = X1;
    g.skip_x[0] = X0; g.skip_x[1] = X1;
    g.skip_s[0] = P.skip + (l*2+0); g.skip_s[1] = P.skip + (l*2+1);
    g.N[0] = Na; g.N[1] = Np; g.blocks0 = ga;
    gemm_kernel<128,0,1,StBF16><<<ga+gp,512,0,stream>>>(g);
  }

  {
    GemmArgs g{};
    g.X[0] = X0; g.X[1] = nullptr;
    g.WT[0] = W(18); g.WT[1] = nullptr;
    g.bias[0] = P.out_b; g.bias[1] = nullptr;
    g.Y[0] = d_out; g.Y[1] = nullptr;
    g.N[0] = Na; g.N[1] = 0; g.blocks0 = ga;
    gemm_kernel<64,0,0,StBF16><<<ga,512,0,stream>>>(g);
  }
}

static size_t plan_bytes(){
  auto al = [](size_t x){ return (x + 255) & ~(size_t)255; };
  size_t t = 0;
  t += 2*(al((size_t)Na*128*2) + al((size_t)Np*128*2));   // X, Q bf16
  t += al((size_t)Na*256*2) + al((size_t)Np*256*2);       // KV bf16
  t += al((size_t)8*16384*4) + al((size_t)8*128*4) + al((size_t)19*16384*2);
  t += al((size_t)(Np+1)*4) + al((size_t)Np*4) + al((size_t)E*4);
  t += al((size_t)(Na+1)*4) + al((size_t)Na*4) + al((size_t)E*4);
  t += al((size_t)1024*4);
  return t;
}

} // namespace

extern "C" void kernel_launch(void* const* d_in, const int* in_sizes, int n_in,
                              void* d_out, int out_size, void* d_ws, size_t ws_size,
                              hipStream_t stream){
  Ptrs P;
  P.x_author = (const float*)d_in[0];
  P.x_paper  = (const float*)d_in[1];
  P.win_w = (const float*)d_in[2];
  P.win_b = (const float*)d_in[3];
  P.kqv_w = (const float*)d_in[4];
  P.kqv_b = (const float*)d_in[5];
  P.a_w   = (const float*)d_in[6];
  P.a_b   = (const float*)d_in[7];
  P.skip  = (const float*)d_in[8];
  P.rel_a = (const float*)d_in[9];
  P.rel_m = (const float*)d_in[10];
  P.rel_p = (const float*)d_in[11];
  P.out_w = (const float*)d_in[12];
  P.out_b = (const float*)d_in[13];
  P.src0 = (const int*)d_in[14];
  P.dst0 = (const int*)d_in[15];
  P.src1 = (const int*)d_in[16];
  P.dst1 = (const int*)d_in[17];

  if (ws_size >= plan_bytes()){
    run_pipeline(P, (float*)d_out, (char*)d_ws, stream);
  } else {
    diag_kernel<<<1,1,0,stream>>>((float*)d_out, (float)((double)ws_size/1.0e6));
  }
}

// Round 13
// 374.933 us; speedup vs baseline: 1.0350x; 1.0350x over previous
//
#include <hip/hip_runtime.h>
#include <math.h>

namespace {

constexpr int Na = 50000, Np = 100000, L = 2, E = 150000;
constexpr int SCAN_TILE = 2048;

typedef __attribute__((ext_vector_type(8))) short short8v;
typedef __attribute__((ext_vector_type(4))) float f32x4;

__device__ inline float geluf(float x){ return 0.5f*x*(1.0f + erff(x*0.7071067811865476f)); }

__device__ inline float bf2f(unsigned short u){ return __uint_as_float(((unsigned)u) << 16); }
__device__ inline unsigned short f2bf(float f){
  unsigned u = __float_as_uint(f);
  u += 0x7FFFu + ((u >> 16) & 1u);   // round-to-nearest-even
  return (unsigned short)(u >> 16);
}
__device__ inline unsigned pk2(float a, float b){
  return (unsigned)f2bf(a) | ((unsigned)f2bf(b) << 16);
}

struct StF32 {
  using T = float;
  static __device__ short8v ld8(const T* __restrict__ p){
    float4 lo = *reinterpret_cast<const float4*>(p);
    float4 hi = *reinterpret_cast<const float4*>(p+4);
    short8v v;
    v[0]=(short)f2bf(lo.x); v[1]=(short)f2bf(lo.y); v[2]=(short)f2bf(lo.z); v[3]=(short)f2bf(lo.w);
    v[4]=(short)f2bf(hi.x); v[5]=(short)f2bf(hi.y); v[6]=(short)f2bf(hi.z); v[7]=(short)f2bf(hi.w);
    return v;
  }
};
struct StBF16 {
  using T = unsigned short;
  static __device__ short8v ld8(const T* __restrict__ p){
    return *reinterpret_cast<const short8v*>(p);
  }
  static __device__ void ld16(const T* __restrict__ p, float* o){
    const uint4* q = reinterpret_cast<const uint4*>(p);
    #pragma unroll
    for (int half = 0; half < 2; ++half){
      uint4 u = q[half];
      o[half*8+0] = bf2f((unsigned short)(u.x & 0xffff));
      o[half*8+1] = bf2f((unsigned short)(u.x >> 16));
      o[half*8+2] = bf2f((unsigned short)(u.y & 0xffff));
      o[half*8+3] = bf2f((unsigned short)(u.y >> 16));
      o[half*8+4] = bf2f((unsigned short)(u.z & 0xffff));
      o[half*8+5] = bf2f((unsigned short)(u.z >> 16));
      o[half*8+6] = bf2f((unsigned short)(u.w & 0xffff));
      o[half*8+7] = bf2f((unsigned short)(u.w >> 16));
    }
  }
};

__global__ void zero_int_kernel(int* __restrict__ p, int n){
  int i = blockIdx.x*256 + threadIdx.x;
  int stride = gridDim.x*256;
  for (; i < n; i += stride) p[i] = 0;
}

__global__ void diag_kernel(float* o, float v){
  if (threadIdx.x == 0 && blockIdx.x == 0) o[0] = v;
}

__global__ void hist_kernel(const int* __restrict__ dst, int* __restrict__ counts, int nE){
  int e = blockIdx.x*256 + threadIdx.x;
  if (e >= nE) return;
  atomicAdd(&counts[dst[e]], 1);
}

// ---- multi-block exclusive scan (3 phases) ----
__global__ void scan_a(const int* __restrict__ counts, int* __restrict__ bsum, int n){
  int base = blockIdx.x*SCAN_TILE;
  int s = 0;
  for (int i = threadIdx.x; i < SCAN_TILE; i += 256){
    int g = base + i;
    s += (g < n) ? counts[g] : 0;
  }
  __shared__ int red[256];
  red[threadIdx.x] = s;
  __syncthreads();
  for (int off = 128; off > 0; off >>= 1){
    if (threadIdx.x < off) red[threadIdx.x] += red[threadIdx.x + off];
    __syncthreads();
  }
  if (threadIdx.x == 0) bsum[blockIdx.x] = red[0];
}

__global__ void scan_b(int* __restrict__ bsum, int nb){
  __shared__ int sh[1024];
  int t = threadIdx.x;
  int v = (t < nb) ? bsum[t] : 0;
  sh[t] = v;
  __syncthreads();
  for (int off = 1; off < 1024; off <<= 1){
    int add = (t >= off) ? sh[t-off] : 0;
    __syncthreads();
    sh[t] += add;
    __syncthreads();
  }
  if (t < nb) bsum[t] = sh[t] - v;   // exclusive
}

__global__ void scan_c(int* __restrict__ counts, const int* __restrict__ bsum,
                       int* __restrict__ rp, int n){
  int base = blockIdx.x*SCAN_TILE;
  __shared__ int sh[SCAN_TILE];
  for (int i = threadIdx.x; i < SCAN_TILE; i += 256){
    int g = base + i;
    sh[i] = (g < n) ? counts[g] : 0;
  }
  __syncthreads();
  int t = threadIdx.x;
  int loc[8], s = 0;
  #pragma unroll
  for (int i = 0; i < 8; ++i){ loc[i] = s; s += sh[t*8 + i]; }
  __shared__ int red[256];
  red[t] = s;
  __syncthreads();
  for (int off = 1; off < 256; off <<= 1){
    int add = (t >= off) ? red[t-off] : 0;
    __syncthreads();
    red[t] += add;
    __syncthreads();
  }
  int texcl = red[t] - s + bsum[blockIdx.x];
  #pragma unroll
  for (int i = 0; i < 8; ++i){
    int g = base + t*8 + i;
    if (g < n){
      int v = texcl + loc[i];
      rp[g] = v;
      counts[g] = v;           // cursor for fill pass
      if (g == n-1) rp[n] = v + sh[t*8 + i];
    }
  }
}

__global__ void fill_slots_kernel(const int* __restrict__ src, const int* __restrict__ dst,
                                  int* __restrict__ cursor, int* __restrict__ slots, int nE){
  int e = blockIdx.x*256 + threadIdx.x;
  if (e >= nE) return;
  int slot = atomicAdd(&cursor[dst[e]], 1);
  slots[slot] = src[e];
}

// Fold rel_a/rel_m into K/V projection weights (fp32).
__global__ void eff_w_kernel(const float* __restrict__ kqv_w, const float* __restrict__ kqv_b,
                             const float* __restrict__ rel_a, const float* __restrict__ rel_m,
                             float* __restrict__ effw, float* __restrict__ effb){
  int idx = blockIdx.x*256 + threadIdx.x;
  if (idx >= 2*2*2*128*128) return;
  int j = idx & 127; int f = (idx >> 7) & 127; int c = idx >> 14;
  int kv = c & 1, t = (c >> 1) & 1, l = c >> 2;
  int h = j >> 4, e2 = j & 15;
  int i = (kv == 0) ? 0 : 2;  // K uses i=0, V uses i=2
  const float* W = kqv_w + ((size_t)(((l*2 + t)*3 + i)*128) + f)*128 + h*16;
  const float* A = ((kv == 0) ? rel_a : rel_m) + ((size_t)(l*2 + t)*8 + h)*256;
  float acc = 0.f;
  #pragma unroll
  for (int d = 0; d < 16; ++d) acc += W[d]*A[d*16 + e2];
  effw[(size_t)c*16384 + f*128 + j] = acc;
  if (f == 0){
    const float* B = kqv_b + (size_t)((l*2 + t)*3 + i)*128 + h*16;
    float ab = 0.f;
    #pragma unroll
    for (int d = 0; d < 16; ++d) ab += B[d]*A[d*16 + e2];
    effb[c*128 + j] = ab;
  }
}

// Convert 19 weight matrices fp32 [k][n] -> bf16 transposed [n][128(k)].
struct PrepSrc { const float* s[19]; };
__global__ void prep_w_kernel(PrepSrc P, unsigned short* __restrict__ wbf){
  int idx = blockIdx.x*256 + threadIdx.x;
  if (idx >= 19*16384) return;
  int s = idx >> 14, j = idx & 16383;
  int n = j >> 7, k = j & 127;
  int nc = (s == 18) ? 64 : 128;
  if (n >= nc) return;
  wbf[(size_t)s*16384 + n*128 + k] = f2bf(P.s[s][(size_t)k*nc + n]);
}

// Stage bf16 WT [rows][128] into LDS with 16B-chunk XOR swizzle (512-thread).
__device__ inline void stage_w(short* Bs, const unsigned short* __restrict__ WT, int t, int rows){
  for (int c = t; c < rows*16; c += 512){
    int r = c >> 4, c16 = c & 15;
    short8v v = *reinterpret_cast<const short8v*>(&WT[r*128 + c16*8]);
    *reinterpret_cast<short8v*>(&Bs[r*128 + ((c16 ^ (r&7))<<3)]) = v;
  }
}

struct GemmArgs {
  const void* X[2];
  const unsigned short* WT[2];
  const float* bias[2];
  void* Y[2];
  const unsigned short* skip_x[2];
  const float* skip_s[2];
  int N[2];
  int blocks0;
};

// MFMA GEMM (512 threads, 8 waves 2x4): Y[N,BN] = epi( X[N,128] @ W + bias ).
// Swapped-operand MFMA -> lane holds 4 consecutive output cols; repack via LDS -> 16B stores.
template<int BN, int RELU_OUT, int SKIP, typename SIn>
__global__ __launch_bounds__(512) void gemm_kernel(GemmArgs Ar)
{
  __shared__ __align__(16) short As[128*128];
  __shared__ __align__(16) char Braw[32768];
  short* Bs = (short*)Braw;
  const int t = threadIdx.x;
  const int part = (blockIdx.x < Ar.blocks0) ? 0 : 1;
  const int bid = part ? (blockIdx.x - Ar.blocks0) : blockIdx.x;
  const typename SIn::T* X = (const typename SIn::T*)Ar.X[part];
  const unsigned short* WT = Ar.WT[part];
  const float* bias = Ar.bias[part];
  const int N = Ar.N[part];
  const int row0 = bid*128;
  for (int c = t; c < 2048; c += 512){
    int r = c >> 4, c16 = c & 15;
    int gr = row0 + r;
    short8v v = (gr < N) ? SIn::ld8(&X[(size_t)gr*128 + c16*8]) : (short8v)0;
    *reinterpret_cast<short8v*>(&As[r*128 + ((c16 ^ (r&7))<<3)]) = v;
  }
  stage_w(Bs, WT, t, BN);
  __syncthreads();
  const int lane = t & 63, wid = t >> 6;
  const int wm = wid >> 2, wn = wid & 3;       // 2 x 4 waves
  constexpr int NR = BN/64;
  const int lr = lane & 15, lk = lane >> 4;
  f32x4 acc[4][NR] = {};
  #pragma unroll
  for (int kk = 0; kk < 4; ++kk){
    int kc = kk*4 + lk;
    short8v a[4], b[NR];
    #pragma unroll
    for (int m = 0; m < 4; ++m){
      int r = wm*64 + m*16 + lr;
      a[m] = *reinterpret_cast<const short8v*>(&As[r*128 + ((kc ^ (r&7))<<3)]);
    }
    #pragma unroll
    for (int n = 0; n < NR; ++n){
      int col = wn*(BN/4) + n*16 + lr;
      b[n] = *reinterpret_cast<const short8v*>(&Bs[col*128 + ((kc ^ (col&7))<<3)]);
    }
    #pragma unroll
    for (int m = 0; m < 4; ++m)
      #pragma unroll
      for (int n = 0; n < NR; ++n)
        acc[m][n] = __builtin_amdgcn_mfma_f32_16x16x32_bf16(b[n], a[m], acc[m][n], 0, 0, 0);
  }
  __syncthreads();   // Bs weight reads done -> reuse as repack buffer

  if constexpr (BN == 128){
    #pragma unroll
    for (int m = 0; m < 4; ++m){
      int row = wm*64 + m*16 + lr;
      #pragma unroll
      for (int n = 0; n < NR; ++n){
        int col0 = wn*32 + n*16 + lk*4;
        float4 b4 = *reinterpret_cast<const float4*>(&bias[col0]);
        float y0 = acc[m][n][0] + b4.x, y1 = acc[m][n][1] + b4.y;
        float y2 = acc[m][n][2] + b4.z, y3 = acc[m][n][3] + b4.w;
        if (RELU_OUT){
          y0 = fmaxf(y0,0.f); y1 = fmaxf(y1,0.f); y2 = fmaxf(y2,0.f); y3 = fmaxf(y3,0.f);
        }
        uint2 pk; pk.x = pk2(y0,y1); pk.y = pk2(y2,y3);
        int c16 = col0 >> 3;
        *reinterpret_cast<uint2*>(&Bs[row*128 + ((c16 ^ (row&7))<<3) + (col0&7)]) = pk;
      }
    }
    __syncthreads();
    float g = 1.f, og = 0.f;
    if (SKIP){ float sv = *Ar.skip_s[part]; g = 1.f/(1.f + expf(-sv)); og = 1.f - g; }
    unsigned short* out = (unsigned short*)Ar.Y[part];
    const unsigned short* skip_x = Ar.skip_x[part];
    for (int c = t; c < 2048; c += 512){
      int r = c >> 4, c16 = c & 15;
      int gr = row0 + r;
      if (gr >= N) continue;
      short8v v = *reinterpret_cast<const short8v*>(&Bs[r*128 + ((c16 ^ (r&7))<<3)]);
      if (SKIP){
        short8v s8 = *reinterpret_cast<const short8v*>(&skip_x[(size_t)gr*128 + c16*8]);
        short8v o8;
        #pragma unroll
        for (int i = 0; i < 8; ++i)
          o8[i] = (short)f2bf(g*bf2f((unsigned short)v[i]) + og*bf2f((unsigned short)s8[i]));
        *reinterpret_cast<short8v*>(&out[(size_t)gr*128 + c16*8]) = o8;
      } else {
        *reinterpret_cast<short8v*>(&out[(size_t)gr*128 + c16*8]) = v;
      }
    }
  } else {
    // BN==64: fp32 repack (32 KB), fp32 coalesced out (classifier)
    float* Bf = (float*)Braw;
    #pragma unroll
    for (int m = 0; m < 4; ++m){
      int row = wm*64 + m*16 + lr;
      int col0 = wn*16 + lk*4;
      float4 b4 = *reinterpret_cast<const float4*>(&bias[col0]);
      float4 y;
      y.x = acc[m][0][0] + b4.x; y.y = acc[m][0][1] + b4.y;
      y.z = acc[m][0][2] + b4.z; y.w = acc[m][0][3] + b4.w;
      int cf = col0 >> 2;
      *reinterpret_cast<float4*>(&Bf[row*64 + ((cf ^ (row&7))<<2)]) = y;
    }
    __syncthreads();
    float* out = (float*)Ar.Y[part];
    for (int c = t; c < 2048; c += 512){
      int r = c >> 4, cf = c & 15;
      int gr = row0 + r;
      if (gr >= N) continue;
      float4 v = *reinterpret_cast<const float4*>(&Bf[r*64 + ((cf ^ (r&7))<<2)]);
      *reinterpret_cast<float4*>(&out[(size_t)gr*64 + cf*4]) = v;
    }
  }
}

struct QkvArgs {
  const unsigned short* X[2];
  const unsigned short* WT[2][3];
  const float* bias[2][3];
  unsigned short* out[2][3];   // Q, K, V
  int N[2];
  int blocks0;
};

// Fused QKV (512 threads): stage X once. Weights round-trip through REGISTERS:
// W(s) regs -> ds_write Bs; prefetch W(s+1) from global DURING MFMA(s) (latency hidden).
__global__ __launch_bounds__(512) void qkv_kernel(QkvArgs Ar)
{
  __shared__ __align__(16) short As[128*128];
  __shared__ __align__(16) short Bs[128*128];
  const int t = threadIdx.x;
  const int part = (blockIdx.x < Ar.blocks0) ? 0 : 1;
  const int bid = part ? (blockIdx.x - Ar.blocks0) : blockIdx.x;
  const unsigned short* X = Ar.X[part];
  const int N = Ar.N[part];
  const int row0 = bid*128;
  for (int c = t; c < 2048; c += 512){
    int r = c >> 4, c16 = c & 15;
    int gr = row0 + r;
    short8v v = (gr < N) ? *reinterpret_cast<const short8v*>(&X[(size_t)gr*128 + c16*8])
                         : (short8v)0;
    *reinterpret_cast<short8v*>(&As[r*128 + ((c16 ^ (r&7))<<3)]) = v;
  }
  // prefetch W0 into regs (4 x 16B per thread)
  short8v w[4];
  {
    const unsigned short* WT0 = Ar.WT[part][0];
    #pragma unroll
    for (int k = 0; k < 4; ++k){
      int c = t + k*512;
      w[k] = *reinterpret_cast<const short8v*>(&WT0[(c >> 4)*128 + (c & 15)*8]);
    }
  }
  __syncthreads();   // As staged
  const int lane = t & 63, wid = t >> 6;
  const int wm = wid >> 2, wn = wid & 3;
  const int lr = lane & 15, lk = lane >> 4;
  #pragma unroll
  for (int s = 0; s < 3; ++s){
    // regs -> Bs (swizzled)
    #pragma unroll
    for (int k = 0; k < 4; ++k){
      int c = t + k*512;
      int r = c >> 4, c16 = c & 15;
      *reinterpret_cast<short8v*>(&Bs[r*128 + ((c16 ^ (r&7))<<3)]) = w[k];
    }
    __syncthreads();   // Bs ready
    if (s < 2){
      const unsigned short* WTn = Ar.WT[part][s+1];
      #pragma unroll
      for (int k = 0; k < 4; ++k){
        int c = t + k*512;
        w[k] = *reinterpret_cast<const short8v*>(&WTn[(c >> 4)*128 + (c & 15)*8]);
      }
    }
    f32x4 acc[4][2] = {};
    #pragma unroll
    for (int kk = 0; kk < 4; ++kk){
      int kc = kk*4 + lk;
      short8v a[4], b[2];
      #pragma unroll
      for (int m = 0; m < 4; ++m){
        int r = wm*64 + m*16 + lr;
        a[m] = *reinterpret_cast<const short8v*>(&As[r*128 + ((kc ^ (r&7))<<3)]);
      }
      #pragma unroll
      for (int n = 0; n < 2; ++n){
        int col = wn*32 + n*16 + lr;
        b[n] = *reinterpret_cast<const short8v*>(&Bs[col*128 + ((kc ^ (col&7))<<3)]);
      }
      #pragma unroll
      for (int m = 0; m < 4; ++m)
        #pragma unroll
        for (int n = 0; n < 2; ++n)
          acc[m][n] = __builtin_amdgcn_mfma_f32_16x16x32_bf16(b[n], a[m], acc[m][n], 0, 0, 0);
    }
    __syncthreads();                   // Bs weight reads done -> repack into Bs
    const float* bi = Ar.bias[part][s];
    #pragma unroll
    for (int m = 0; m < 4; ++m){
      int row = wm*64 + m*16 + lr;
      #pragma unroll
      for (int n = 0; n < 2; ++n){
        int col0 = wn*32 + n*16 + lk*4;
        float4 b4 = *reinterpret_cast<const float4*>(&bi[col0]);
        uint2 pk;
        pk.x = pk2(acc[m][n][0] + b4.x, acc[m][n][1] + b4.y);
        pk.y = pk2(acc[m][n][2] + b4.z, acc[m][n][3] + b4.w);
        int c16 = col0 >> 3;
        *reinterpret_cast<uint2*>(&Bs[row*128 + ((c16 ^ (row&7))<<3) + (col0&7)]) = pk;
      }
    }
    __syncthreads();
    unsigned short* out = Ar.out[part][s];
    for (int c = t; c < 2048; c += 512){
      int r = c >> 4, c16 = c & 15;
      int gr = row0 + r;
      if (gr >= N) continue;
      short8v v = *reinterpret_cast<const short8v*>(&Bs[r*128 + ((c16 ^ (r&7))<<3)]);
      *reinterpret_cast<short8v*>(&out[(size_t)gr*128 + c16*8]) = v;
    }
    __syncthreads();   // readout done before Bs is overwritten next iter
  }
}

struct AttnArgs {
  unsigned short* QA[2];
  const unsigned short* K[2];
  const unsigned short* V[2];
  const int* rp[2];
  const int* slots[2];
  const float* relp[2];
  int N[2];
  int blocks0;
};

// Fused attention (both directions, one launch): thread per (dst node, head).
// No-max softmax (|alpha| << 1 -> exp safe in fp32; identical math). Unroll x2, loads first.
// gelu applied to aggregate before store (a_lin reads pre-activated input).
__global__ void attn_gather_kernel(AttnArgs Ar){
  const int part = (blockIdx.x < Ar.blocks0) ? 0 : 1;
  const int bid = part ? (blockIdx.x - Ar.blocks0) : blockIdx.x;
  int idx = bid*256 + threadIdx.x;
  const int N = Ar.N[part];
  if (idx >= N*8) return;
  int h = idx & 7, n = idx >> 3;
  unsigned short* QA = Ar.QA[part];
  const unsigned short* K = Ar.K[part];
  const unsigned short* V = Ar.V[part];
  float q[16];
  StBF16::ld16(&QA[(size_t)n*128 + h*16], q);
  float scale_h = Ar.relp[part][h]*0.25f;
  float s = 0.f, acc[16];
  #pragma unroll
  for (int i = 0; i < 16; ++i) acc[i] = 0.f;
  int b = Ar.rp[part][n], e = Ar.rp[part][n+1];
  const int* slots = Ar.slots[part];
  int j = b;
  for (; j + 2 <= e; j += 2){
    int sv0 = slots[j], sv1 = slots[j+1];
    float kf0[16], vf0[16], kf1[16], vf1[16];
    StBF16::ld16(&K[(size_t)sv0*128 + h*16], kf0);
    StBF16::ld16(&V[(size_t)sv0*128 + h*16], vf0);
    StBF16::ld16(&K[(size_t)sv1*128 + h*16], kf1);
    StBF16::ld16(&V[(size_t)sv1*128 + h*16], vf1);
    float a0 = 0.f, a1 = 0.f;
    #pragma unroll
    for (int i = 0; i < 16; ++i){ a0 += q[i]*kf0[i]; a1 += q[i]*kf1[i]; }
    float p0 = expf(a0*scale_h), p1 = expf(a1*scale_h);
    s += p0 + p1;
    #pragma unroll
    for (int i = 0; i < 16; ++i) acc[i] += p0*vf0[i] + p1*vf1[i];
  }
  if (j < e){
    int sv = slots[j];
    float kf[16], vf[16];
    StBF16::ld16(&K[(size_t)sv*128 + h*16], kf);
    StBF16::ld16(&V[(size_t)sv*128 + h*16], vf);
    float a = 0.f;
    #pragma unroll
    for (int i = 0; i < 16; ++i) a += q[i]*kf[i];
    float p = expf(a*scale_h);
    s += p;
    #pragma unroll
    for (int i = 0; i < 16; ++i) acc[i] += p*vf[i];
  }
  float inv = 1.f/(s + 1e-16f);
  #pragma unroll
  for (int i = 0; i < 16; ++i)
    QA[(size_t)n*128 + h*16 + i] = f2bf(geluf(acc[i]*inv));
}

struct Ptrs {
  const float *x_author, *x_paper, *win_w, *win_b, *kqv_w, *kqv_b, *a_w, *a_b;
  const float *skip, *rel_a, *rel_m, *rel_p, *out_w, *out_b;
  const int *src0, *dst0, *src1, *dst1;
};

static void run_pipeline(const Ptrs& P, float* d_out, char* ws, hipStream_t stream){
  using BF = unsigned short;
  size_t off = 0;
  auto alloc = [&](size_t bytes) -> void* {
    void* p = ws + off;
    off += (bytes + 255) & ~(size_t)255;
    return p;
  };
  BF* X0 = (BF*)alloc((size_t)Na*128*2);
  BF* X1 = (BF*)alloc((size_t)Np*128*2);
  BF* Q0 = (BF*)alloc((size_t)Na*128*2);   // Q -> agg in place
  BF* Q1 = (BF*)alloc((size_t)Np*128*2);
  BF* K0 = (BF*)alloc((size_t)Na*128*2);
  BF* K1 = (BF*)alloc((size_t)Np*128*2);
  BF* V0 = (BF*)alloc((size_t)Na*128*2);
  BF* V1 = (BF*)alloc((size_t)Np*128*2);
  float* effw = (float*)alloc((size_t)8*16384*4);
  float* effb = (float*)alloc((size_t)8*128*4);
  BF* wbf = (BF*)alloc((size_t)19*16384*2);
  int* rp0   = (int*)alloc((size_t)(Np+1)*4);
  int* cur0  = (int*)alloc((size_t)Np*4);
  int* slot0 = (int*)alloc((size_t)E*4);
  int* rp1   = (int*)alloc((size_t)(Na+1)*4);
  int* cur1  = (int*)alloc((size_t)Na*4);
  int* slot1 = (int*)alloc((size_t)E*4);
  int* bsum  = (int*)alloc((size_t)1024*4);

  auto cdiv = [](int a, int b){ return (a+b-1)/b; };
  const int geE = cdiv(E, 256);
  const int ga = cdiv(Na, 128), gp = cdiv(Np, 128);
  const int sb0 = cdiv(Np, SCAN_TILE), sb1 = cdiv(Na, SCAN_TILE);

  eff_w_kernel<<<512, 256, 0, stream>>>(P.kqv_w, P.kqv_b, P.rel_a, P.rel_m, effw, effb);

  // weight prep: slots 0-1 win, 2-5 Q(l,t), 6-9 K, 10-13 V, 14-17 a_w, 18 out_w
  PrepSrc ps;
  ps.s[0] = P.win_w; ps.s[1] = P.win_w + 16384;
  for (int l = 0; l < 2; ++l)
    for (int t = 0; t < 2; ++t){
      ps.s[2 + l*2 + t]  = P.kqv_w + (size_t)((l*2+t)*3+1)*16384;
      ps.s[6 + l*2 + t]  = effw + (size_t)(l*4+t*2+0)*16384;
      ps.s[10 + l*2 + t] = effw + (size_t)(l*4+t*2+1)*16384;
      ps.s[14 + l*2 + t] = P.a_w + (size_t)(l*2+t)*16384;
    }
  ps.s[18] = P.out_w;
  prep_w_kernel<<<cdiv(19*16384,256),256,0,stream>>>(ps, wbf);

  // ---- CSR build ----
  zero_int_kernel<<<512,256,0,stream>>>(cur0, Np);
  zero_int_kernel<<<512,256,0,stream>>>(cur1, Na);
  hist_kernel<<<geE,256,0,stream>>>(P.dst0, cur0, E);
  hist_kernel<<<geE,256,0,stream>>>(P.dst1, cur1, E);
  scan_a<<<sb0,256,0,stream>>>(cur0, bsum, Np);
  scan_b<<<1,1024,0,stream>>>(bsum, sb0);
  scan_c<<<sb0,256,0,stream>>>(cur0, bsum, rp0, Np);
  scan_a<<<sb1,256,0,stream>>>(cur1, bsum, Na);
  scan_b<<<1,1024,0,stream>>>(bsum, sb1);
  scan_c<<<sb1,256,0,stream>>>(cur1, bsum, rp1, Na);
  fill_slots_kernel<<<geE,256,0,stream>>>(P.src0, P.dst0, cur0, slot0, E);
  fill_slots_kernel<<<geE,256,0,stream>>>(P.src1, P.dst1, cur1, slot1, E);

  auto W = [&](int s){ return wbf + (size_t)s*16384; };

  // input projections + relu (fp32 in, bf16 out) — merged pair
  {
    GemmArgs g{};
    g.X[0] = P.x_author; g.X[1] = P.x_paper;
    g.WT[0] = W(0); g.WT[1] = W(1);
    g.bias[0] = P.win_b; g.bias[1] = P.win_b + 128;
    g.Y[0] = X0; g.Y[1] = X1;
    g.N[0] = Na; g.N[1] = Np; g.blocks0 = ga;
    gemm_kernel<128,1,0,StF32><<<ga+gp,512,0,stream>>>(g);
  }

  const int ab0 = cdiv(Np*8,256), ab1 = cdiv(Na*8,256);

  for (int l = 0; l < L; ++l){
    QkvArgs q{};
    q.X[0] = X0; q.X[1] = X1;
    for (int t2 = 0; t2 < 2; ++t2){
      q.WT[t2][0] = W(2+l*2+t2); q.WT[t2][1] = W(6+l*2+t2); q.WT[t2][2] = W(10+l*2+t2);
      q.bias[t2][0] = P.kqv_b + ((l*2+t2)*3+1)*128;
      q.bias[t2][1] = effb + (l*4+t2*2+0)*128;
      q.bias[t2][2] = effb + (l*4+t2*2+1)*128;
    }
    q.out[0][0] = Q0; q.out[0][1] = K0; q.out[0][2] = V0;
    q.out[1][0] = Q1; q.out[1][1] = K1; q.out[1][2] = V1;
    q.N[0] = Na; q.N[1] = Np; q.blocks0 = ga;
    qkv_kernel<<<ga+gp,512,0,stream>>>(q);

    AttnArgs a{};
    a.QA[0] = Q1; a.K[0] = K0; a.V[0] = V0; a.rp[0] = rp0; a.slots[0] = slot0;
    a.relp[0] = P.rel_p + (l*2+0)*8; a.N[0] = Np;
    a.QA[1] = Q0; a.K[1] = K1; a.V[1] = V1; a.rp[1] = rp1; a.slots[1] = slot1;
    a.relp[1] = P.rel_p + (l*2+1)*8; a.N[1] = Na;
    a.blocks0 = ab0;
    attn_gather_kernel<<<ab0+ab1,256,0,stream>>>(a);

    GemmArgs g{};
    g.X[0] = Q0; g.X[1] = Q1;
    g.WT[0] = W(14+l*2+0); g.WT[1] = W(14+l*2+1);
    g.bias[0] = P.a_b + (l*2+0)*128; g.bias[1] = P.a_b + (l*2+1)*128;
    g.Y[0] = X0; g.Y[1] = X1;
    g.skip_x[0] = X0; g.skip_x[1] = X1;
    g.skip_s[0] = P.skip + (l*2+0); g.skip_s[1] = P.skip + (l*2+1);
    g.N[0] = Na; g.N[1] = Np; g.blocks0 = ga;
    gemm_kernel<128,0,1,StBF16><<<ga+gp,512,0,stream>>>(g);
  }

  {
    GemmArgs g{};
    g.X[0] = X0; g.X[1] = nullptr;
    g.WT[0] = W(18); g.WT[1] = nullptr;
    g.bias[0] = P.out_b; g.bias[1] = nullptr;
    g.Y[0] = d_out; g.Y[1] = nullptr;
    g.N[0] = Na; g.N[1] = 0; g.blocks0 = ga;
    gemm_kernel<64,0,0,StBF16><<<ga,512,0,stream>>>(g);
  }
}

static size_t plan_bytes(){
  auto al = [](size_t x){ return (x + 255) & ~(size_t)255; };
  size_t t = 0;
  t += 4*(al((size_t)Na*128*2) + al((size_t)Np*128*2));   // X,Q,K,V bf16
  t += al((size_t)8*16384*4) + al((size_t)8*128*4) + al((size_t)19*16384*2);
  t += al((size_t)(Np+1)*4) + al((size_t)Np*4) + al((size_t)E*4);
  t += al((size_t)(Na+1)*4) + al((size_t)Na*4) + al((size_t)E*4);
  t += al((size_t)1024*4);
  return t;
}

} // namespace

extern "C" void kernel_launch(void* const* d_in, const int* in_sizes, int n_in,
                              void* d_out, int out_size, void* d_ws, size_t ws_size,
                              hipStream_t stream){
  Ptrs P;
  P.x_author = (const float*)d_in[0];
  P.x_paper  = (const float*)d_in[1];
  P.win_w = (const float*)d_in[2];
  P.win_b = (const float*)d_in[3];
  P.kqv_w = (const float*)d_in[4];
  P.kqv_b = (const float*)d_in[5];
  P.a_w   = (const float*)d_in[6];
  P.a_b   = (const float*)d_in[7];
  P.skip  = (const float*)d_in[8];
  P.rel_a = (const float*)d_in[9];
  P.rel_m = (const float*)d_in[10];
  P.rel_p = (const float*)d_in[11];
  P.out_w = (const float*)d_in[12];
  P.out_b = (const float*)d_in[13];
  P.src0 = (const int*)d_in[14];
  P.dst0 = (const int*)d_in[15];
  P.src1 = (const int*)d_in[16];
  P.dst1 = (const int*)d_in[17];

  if (ws_size >= plan_bytes()){
    run_pipeline(P, (float*)d_out, (char*)d_ws, stream);
  } else {
    diag_kernel<<<1,1,0,stream>>>((float*)d_out, (float)((double)ws_size/1.0e6));
  }
}

// Round 14
// 338.472 us; speedup vs baseline: 1.1465x; 1.1077x over previous
//
#include <hip/hip_runtime.h>
#include <math.h>

namespace {

constexpr int Na = 50000, Np = 100000, L = 2, E = 150000;
constexpr int SCAN_TILE = 2048;

typedef __attribute__((ext_vector_type(8))) short short8v;
typedef __attribute__((ext_vector_type(4))) float f32x4;

__device__ inline float geluf(float x){ return 0.5f*x*(1.0f + erff(x*0.7071067811865476f)); }

__device__ inline float bf2f(unsigned short u){ return __uint_as_float(((unsigned)u) << 16); }
__device__ inline unsigned short f2bf(float f){
  unsigned u = __float_as_uint(f);
  u += 0x7FFFu + ((u >> 16) & 1u);   // round-to-nearest-even
  return (unsigned short)(u >> 16);
}
__device__ inline unsigned pk2(float a, float b){
  return (unsigned)f2bf(a) | ((unsigned)f2bf(b) << 16);
}

struct StF32 {
  using T = float;
  static __device__ short8v ld8(const T* __restrict__ p){
    float4 lo = *reinterpret_cast<const float4*>(p);
    float4 hi = *reinterpret_cast<const float4*>(p+4);
    short8v v;
    v[0]=(short)f2bf(lo.x); v[1]=(short)f2bf(lo.y); v[2]=(short)f2bf(lo.z); v[3]=(short)f2bf(lo.w);
    v[4]=(short)f2bf(hi.x); v[5]=(short)f2bf(hi.y); v[6]=(short)f2bf(hi.z); v[7]=(short)f2bf(hi.w);
    return v;
  }
};
struct StBF16 {
  using T = unsigned short;
  static __device__ short8v ld8(const T* __restrict__ p){
    return *reinterpret_cast<const short8v*>(p);
  }
  static __device__ void ld16(const T* __restrict__ p, float* o){
    const uint4* q = reinterpret_cast<const uint4*>(p);
    #pragma unroll
    for (int half = 0; half < 2; ++half){
      uint4 u = q[half];
      o[half*8+0] = bf2f((unsigned short)(u.x & 0xffff));
      o[half*8+1] = bf2f((unsigned short)(u.x >> 16));
      o[half*8+2] = bf2f((unsigned short)(u.y & 0xffff));
      o[half*8+3] = bf2f((unsigned short)(u.y >> 16));
      o[half*8+4] = bf2f((unsigned short)(u.z & 0xffff));
      o[half*8+5] = bf2f((unsigned short)(u.z >> 16));
      o[half*8+6] = bf2f((unsigned short)(u.w & 0xffff));
      o[half*8+7] = bf2f((unsigned short)(u.w >> 16));
    }
  }
};

__global__ void zero_int_kernel(int* __restrict__ p, int n){
  int i = blockIdx.x*256 + threadIdx.x;
  int stride = gridDim.x*256;
  for (; i < n; i += stride) p[i] = 0;
}

__global__ void diag_kernel(float* o, float v){
  if (threadIdx.x == 0 && blockIdx.x == 0) o[0] = v;
}

__global__ void hist_kernel(const int* __restrict__ dst, int* __restrict__ counts, int nE){
  int e = blockIdx.x*256 + threadIdx.x;
  if (e >= nE) return;
  atomicAdd(&counts[dst[e]], 1);
}

// ---- multi-block exclusive scan (3 phases) ----
__global__ void scan_a(const int* __restrict__ counts, int* __restrict__ bsum, int n){
  int base = blockIdx.x*SCAN_TILE;
  int s = 0;
  for (int i = threadIdx.x; i < SCAN_TILE; i += 256){
    int g = base + i;
    s += (g < n) ? counts[g] : 0;
  }
  __shared__ int red[256];
  red[threadIdx.x] = s;
  __syncthreads();
  for (int off = 128; off > 0; off >>= 1){
    if (threadIdx.x < off) red[threadIdx.x] += red[threadIdx.x + off];
    __syncthreads();
  }
  if (threadIdx.x == 0) bsum[blockIdx.x] = red[0];
}

__global__ void scan_b(int* __restrict__ bsum, int nb){
  __shared__ int sh[1024];
  int t = threadIdx.x;
  int v = (t < nb) ? bsum[t] : 0;
  sh[t] = v;
  __syncthreads();
  for (int off = 1; off < 1024; off <<= 1){
    int add = (t >= off) ? sh[t-off] : 0;
    __syncthreads();
    sh[t] += add;
    __syncthreads();
  }
  if (t < nb) bsum[t] = sh[t] - v;   // exclusive
}

__global__ void scan_c(int* __restrict__ counts, const int* __restrict__ bsum,
                       int* __restrict__ rp, int n){
  int base = blockIdx.x*SCAN_TILE;
  __shared__ int sh[SCAN_TILE];
  for (int i = threadIdx.x; i < SCAN_TILE; i += 256){
    int g = base + i;
    sh[i] = (g < n) ? counts[g] : 0;
  }
  __syncthreads();
  int t = threadIdx.x;
  int loc[8], s = 0;
  #pragma unroll
  for (int i = 0; i < 8; ++i){ loc[i] = s; s += sh[t*8 + i]; }
  __shared__ int red[256];
  red[t] = s;
  __syncthreads();
  for (int off = 1; off < 256; off <<= 1){
    int add = (t >= off) ? red[t-off] : 0;
    __syncthreads();
    red[t] += add;
    __syncthreads();
  }
  int texcl = red[t] - s + bsum[blockIdx.x];
  #pragma unroll
  for (int i = 0; i < 8; ++i){
    int g = base + t*8 + i;
    if (g < n){
      int v = texcl + loc[i];
      rp[g] = v;
      counts[g] = v;           // cursor for fill pass
      if (g == n-1) rp[n] = v + sh[t*8 + i];
    }
  }
}

__global__ void fill_slots_kernel(const int* __restrict__ src, const int* __restrict__ dst,
                                  int* __restrict__ cursor, int* __restrict__ slots, int nE){
  int e = blockIdx.x*256 + threadIdx.x;
  if (e >= nE) return;
  int slot = atomicAdd(&cursor[dst[e]], 1);
  slots[slot] = src[e];
}

// Fold rel_a/rel_m into K/V projection weights (fp32).
__global__ void eff_w_kernel(const float* __restrict__ kqv_w, const float* __restrict__ kqv_b,
                             const float* __restrict__ rel_a, const float* __restrict__ rel_m,
                             float* __restrict__ effw, float* __restrict__ effb){
  int idx = blockIdx.x*256 + threadIdx.x;
  if (idx >= 2*2*2*128*128) return;
  int j = idx & 127; int f = (idx >> 7) & 127; int c = idx >> 14;
  int kv = c & 1, t = (c >> 1) & 1, l = c >> 2;
  int h = j >> 4, e2 = j & 15;
  int i = (kv == 0) ? 0 : 2;  // K uses i=0, V uses i=2
  const float* W = kqv_w + ((size_t)(((l*2 + t)*3 + i)*128) + f)*128 + h*16;
  const float* A = ((kv == 0) ? rel_a : rel_m) + ((size_t)(l*2 + t)*8 + h)*256;
  float acc = 0.f;
  #pragma unroll
  for (int d = 0; d < 16; ++d) acc += W[d]*A[d*16 + e2];
  effw[(size_t)c*16384 + f*128 + j] = acc;
  if (f == 0){
    const float* B = kqv_b + (size_t)((l*2 + t)*3 + i)*128 + h*16;
    float ab = 0.f;
    #pragma unroll
    for (int d = 0; d < 16; ++d) ab += B[d]*A[d*16 + e2];
    effb[c*128 + j] = ab;
  }
}

// Convert 19 weight matrices fp32 [k][n] -> bf16 transposed [n][128(k)].
struct PrepSrc { const float* s[19]; };
__global__ void prep_w_kernel(PrepSrc P, unsigned short* __restrict__ wbf){
  int idx = blockIdx.x*256 + threadIdx.x;
  if (idx >= 19*16384) return;
  int s = idx >> 14, j = idx & 16383;
  int n = j >> 7, k = j & 127;
  int nc = (s == 18) ? 64 : 128;
  if (n >= nc) return;
  wbf[(size_t)s*16384 + n*128 + k] = f2bf(P.s[s][(size_t)k*nc + n]);
}

// Stage bf16 WT [rows][128] into LDS with 16B-chunk XOR swizzle (512-thread).
__device__ inline void stage_w(short* Bs, const unsigned short* __restrict__ WT, int t, int rows){
  for (int c = t; c < rows*16; c += 512){
    int r = c >> 4, c16 = c & 15;
    short8v v = *reinterpret_cast<const short8v*>(&WT[r*128 + c16*8]);
    *reinterpret_cast<short8v*>(&Bs[r*128 + ((c16 ^ (r&7))<<3)]) = v;
  }
}

struct GemmArgs {
  const void* X[2];
  const unsigned short* WT[2];
  const float* bias[2];
  void* Y[2];
  const unsigned short* skip_x[2];
  const float* skip_s[2];
  int N[2];
  int blocks0;
};

// MFMA GEMM (512 threads, 8 waves 2x4): Y[N,BN] = epi( act(X[N,128]) @ W + bias ).
// Swapped-operand MFMA -> lane holds 4 consecutive output cols; repack via LDS -> 16B stores.
template<int BN, int GELU_IN, int RELU_OUT, int SKIP, typename SIn>
__global__ __launch_bounds__(512) void gemm_kernel(GemmArgs Ar)
{
  __shared__ __align__(16) short As[128*128];
  __shared__ __align__(16) char Braw[32768];
  short* Bs = (short*)Braw;
  const int t = threadIdx.x;
  const int part = (blockIdx.x < Ar.blocks0) ? 0 : 1;
  const int bid = part ? (blockIdx.x - Ar.blocks0) : blockIdx.x;
  const typename SIn::T* X = (const typename SIn::T*)Ar.X[part];
  const unsigned short* WT = Ar.WT[part];
  const float* bias = Ar.bias[part];
  const int N = Ar.N[part];
  const int row0 = bid*128;
  for (int c = t; c < 2048; c += 512){
    int r = c >> 4, c16 = c & 15;
    int gr = row0 + r;
    short8v v;
    if (gr < N){
      v = SIn::ld8(&X[(size_t)gr*128 + c16*8]);
      if (GELU_IN){
        #pragma unroll
        for (int i = 0; i < 8; ++i){
          float f = geluf(bf2f((unsigned short)v[i]));
          v[i] = (short)f2bf(f);
        }
      }
    } else {
      v = (short8v)0;
    }
    *reinterpret_cast<short8v*>(&As[r*128 + ((c16 ^ (r&7))<<3)]) = v;
  }
  stage_w(Bs, WT, t, BN);
  __syncthreads();
  const int lane = t & 63, wid = t >> 6;
  const int wm = wid >> 2, wn = wid & 3;       // 2 x 4 waves
  constexpr int NR = BN/64;
  const int lr = lane & 15, lk = lane >> 4;
  f32x4 acc[4][NR] = {};
  #pragma unroll
  for (int kk = 0; kk < 4; ++kk){
    int kc = kk*4 + lk;
    short8v a[4], b[NR];
    #pragma unroll
    for (int m = 0; m < 4; ++m){
      int r = wm*64 + m*16 + lr;
      a[m] = *reinterpret_cast<const short8v*>(&As[r*128 + ((kc ^ (r&7))<<3)]);
    }
    #pragma unroll
    for (int n = 0; n < NR; ++n){
      int col = wn*(BN/4) + n*16 + lr;
      b[n] = *reinterpret_cast<const short8v*>(&Bs[col*128 + ((kc ^ (col&7))<<3)]);
    }
    #pragma unroll
    for (int m = 0; m < 4; ++m)
      #pragma unroll
      for (int n = 0; n < NR; ++n)
        acc[m][n] = __builtin_amdgcn_mfma_f32_16x16x32_bf16(b[n], a[m], acc[m][n], 0, 0, 0);
  }
  __syncthreads();   // Bs weight reads done -> reuse as repack buffer

  if constexpr (BN == 128){
    #pragma unroll
    for (int m = 0; m < 4; ++m){
      int row = wm*64 + m*16 + lr;
      #pragma unroll
      for (int n = 0; n < NR; ++n){
        int col0 = wn*32 + n*16 + lk*4;
        float4 b4 = *reinterpret_cast<const float4*>(&bias[col0]);
        float y0 = acc[m][n][0] + b4.x, y1 = acc[m][n][1] + b4.y;
        float y2 = acc[m][n][2] + b4.z, y3 = acc[m][n][3] + b4.w;
        if (RELU_OUT){
          y0 = fmaxf(y0,0.f); y1 = fmaxf(y1,0.f); y2 = fmaxf(y2,0.f); y3 = fmaxf(y3,0.f);
        }
        uint2 pk; pk.x = pk2(y0,y1); pk.y = pk2(y2,y3);
        int c16 = col0 >> 3;
        *reinterpret_cast<uint2*>(&Bs[row*128 + ((c16 ^ (row&7))<<3) + (col0&7)]) = pk;
      }
    }
    __syncthreads();
    float g = 1.f, og = 0.f;
    if (SKIP){ float sv = *Ar.skip_s[part]; g = 1.f/(1.f + expf(-sv)); og = 1.f - g; }
    unsigned short* out = (unsigned short*)Ar.Y[part];
    const unsigned short* skip_x = Ar.skip_x[part];
    for (int c = t; c < 2048; c += 512){
      int r = c >> 4, c16 = c & 15;
      int gr = row0 + r;
      if (gr >= N) continue;
      short8v v = *reinterpret_cast<const short8v*>(&Bs[r*128 + ((c16 ^ (r&7))<<3)]);
      if (SKIP){
        short8v s8 = *reinterpret_cast<const short8v*>(&skip_x[(size_t)gr*128 + c16*8]);
        short8v o8;
        #pragma unroll
        for (int i = 0; i < 8; ++i)
          o8[i] = (short)f2bf(g*bf2f((unsigned short)v[i]) + og*bf2f((unsigned short)s8[i]));
        *reinterpret_cast<short8v*>(&out[(size_t)gr*128 + c16*8]) = o8;
      } else {
        *reinterpret_cast<short8v*>(&out[(size_t)gr*128 + c16*8]) = v;
      }
    }
  } else {
    // BN==64: fp32 repack (32 KB), fp32 coalesced out (classifier)
    float* Bf = (float*)Braw;
    #pragma unroll
    for (int m = 0; m < 4; ++m){
      int row = wm*64 + m*16 + lr;
      int col0 = wn*16 + lk*4;
      float4 b4 = *reinterpret_cast<const float4*>(&bias[col0]);
      float4 y;
      y.x = acc[m][0][0] + b4.x; y.y = acc[m][0][1] + b4.y;
      y.z = acc[m][0][2] + b4.z; y.w = acc[m][0][3] + b4.w;
      int cf = col0 >> 2;
      *reinterpret_cast<float4*>(&Bf[row*64 + ((cf ^ (row&7))<<2)]) = y;
    }
    __syncthreads();
    float* out = (float*)Ar.Y[part];
    for (int c = t; c < 2048; c += 512){
      int r = c >> 4, cf = c & 15;
      int gr = row0 + r;
      if (gr >= N) continue;
      float4 v = *reinterpret_cast<const float4*>(&Bf[r*64 + ((cf ^ (r&7))<<2)]);
      *reinterpret_cast<float4*>(&out[(size_t)gr*64 + cf*4]) = v;
    }
  }
}

struct QkvArgs {
  const unsigned short* X[2];
  const unsigned short* WT[2][3];
  const float* bias[2][3];
  unsigned short* out[2][3];   // Q, K, V
  int N[2];
  int blocks0;
};

// Fused QKV (512 threads): stage X once. Weights round-trip through REGISTERS:
// W(s) regs -> ds_write Bs; prefetch W(s+1) from global DURING MFMA(s) (latency hidden).
__global__ __launch_bounds__(512) void qkv_kernel(QkvArgs Ar)
{
  __shared__ __align__(16) short As[128*128];
  __shared__ __align__(16) short Bs[128*128];
  const int t = threadIdx.x;
  const int part = (blockIdx.x < Ar.blocks0) ? 0 : 1;
  const int bid = part ? (blockIdx.x - Ar.blocks0) : blockIdx.x;
  const unsigned short* X = Ar.X[part];
  const int N = Ar.N[part];
  const int row0 = bid*128;
  for (int c = t; c < 2048; c += 512){
    int r = c >> 4, c16 = c & 15;
    int gr = row0 + r;
    short8v v = (gr < N) ? *reinterpret_cast<const short8v*>(&X[(size_t)gr*128 + c16*8])
                         : (short8v)0;
    *reinterpret_cast<short8v*>(&As[r*128 + ((c16 ^ (r&7))<<3)]) = v;
  }
  // prefetch W0 into regs (4 x 16B per thread)
  short8v w[4];
  {
    const unsigned short* WT0 = Ar.WT[part][0];
    #pragma unroll
    for (int k = 0; k < 4; ++k){
      int c = t + k*512;
      w[k] = *reinterpret_cast<const short8v*>(&WT0[(c >> 4)*128 + (c & 15)*8]);
    }
  }
  __syncthreads();   // As staged
  const int lane = t & 63, wid = t >> 6;
  const int wm = wid >> 2, wn = wid & 3;
  const int lr = lane & 15, lk = lane >> 4;
  #pragma unroll
  for (int s = 0; s < 3; ++s){
    // regs -> Bs (swizzled)
    #pragma unroll
    for (int k = 0; k < 4; ++k){
      int c = t + k*512;
      int r = c >> 4, c16 = c & 15;
      *reinterpret_cast<short8v*>(&Bs[r*128 + ((c16 ^ (r&7))<<3)]) = w[k];
    }
    __syncthreads();   // Bs ready
    if (s < 2){
      const unsigned short* WTn = Ar.WT[part][s+1];
      #pragma unroll
      for (int k = 0; k < 4; ++k){
        int c = t + k*512;
        w[k] = *reinterpret_cast<const short8v*>(&WTn[(c >> 4)*128 + (c & 15)*8]);
      }
    }
    f32x4 acc[4][2] = {};
    #pragma unroll
    for (int kk = 0; kk < 4; ++kk){
      int kc = kk*4 + lk;
      short8v a[4], b[2];
      #pragma unroll
      for (int m = 0; m < 4; ++m){
        int r = wm*64 + m*16 + lr;
        a[m] = *reinterpret_cast<const short8v*>(&As[r*128 + ((kc ^ (r&7))<<3)]);
      }
      #pragma unroll
      for (int n = 0; n < 2; ++n){
        int col = wn*32 + n*16 + lr;
        b[n] = *reinterpret_cast<const short8v*>(&Bs[col*128 + ((kc ^ (col&7))<<3)]);
      }
      #pragma unroll
      for (int m = 0; m < 4; ++m)
        #pragma unroll
        for (int n = 0; n < 2; ++n)
          acc[m][n] = __builtin_amdgcn_mfma_f32_16x16x32_bf16(b[n], a[m], acc[m][n], 0, 0, 0);
    }
    __syncthreads();                   // Bs weight reads done -> repack into Bs
    const float* bi = Ar.bias[part][s];
    #pragma unroll
    for (int m = 0; m < 4; ++m){
      int row = wm*64 + m*16 + lr;
      #pragma unroll
      for (int n = 0; n < 2; ++n){
        int col0 = wn*32 + n*16 + lk*4;
        float4 b4 = *reinterpret_cast<const float4*>(&bi[col0]);
        uint2 pk;
        pk.x = pk2(acc[m][n][0] + b4.x, acc[m][n][1] + b4.y);
        pk.y = pk2(acc[m][n][2] + b4.z, acc[m][n][3] + b4.w);
        int c16 = col0 >> 3;
        *reinterpret_cast<uint2*>(&Bs[row*128 + ((c16 ^ (row&7))<<3) + (col0&7)]) = pk;
      }
    }
    __syncthreads();
    unsigned short* out = Ar.out[part][s];
    for (int c = t; c < 2048; c += 512){
      int r = c >> 4, c16 = c & 15;
      int gr = row0 + r;
      if (gr >= N) continue;
      short8v v = *reinterpret_cast<const short8v*>(&Bs[r*128 + ((c16 ^ (r&7))<<3)]);
      *reinterpret_cast<short8v*>(&out[(size_t)gr*128 + c16*8]) = v;
    }
    __syncthreads();   // readout done before Bs is overwritten next iter
  }
}

struct AttnArgs {
  unsigned short* QA[2];
  const unsigned short* K[2];
  const unsigned short* V[2];
  const int* rp[2];
  const int* slots[2];
  const float* relp[2];
  int N[2];
  int blocks0;
};

// Fused attention (both directions, one launch): thread per (dst node, head).
// No-max softmax (|alpha| << 1 -> exp safe in fp32; identical math). Unroll x2, loads first.
// NO gelu here (a_lin applies it in staging — cheaper there; r10/r13 A/B evidence).
__global__ void attn_gather_kernel(AttnArgs Ar){
  const int part = (blockIdx.x < Ar.blocks0) ? 0 : 1;
  const int bid = part ? (blockIdx.x - Ar.blocks0) : blockIdx.x;
  int idx = bid*256 + threadIdx.x;
  const int N = Ar.N[part];
  if (idx >= N*8) return;
  int h = idx & 7, n = idx >> 3;
  unsigned short* QA = Ar.QA[part];
  const unsigned short* K = Ar.K[part];
  const unsigned short* V = Ar.V[part];
  float q[16];
  StBF16::ld16(&QA[(size_t)n*128 + h*16], q);
  float scale_h = Ar.relp[part][h]*0.25f;
  float s = 0.f, acc[16];
  #pragma unroll
  for (int i = 0; i < 16; ++i) acc[i] = 0.f;
  int b = Ar.rp[part][n], e = Ar.rp[part][n+1];
  const int* slots = Ar.slots[part];
  int j = b;
  for (; j + 2 <= e; j += 2){
    int sv0 = slots[j], sv1 = slots[j+1];
    float kf0[16], vf0[16], kf1[16], vf1[16];
    StBF16::ld16(&K[(size_t)sv0*128 + h*16], kf0);
    StBF16::ld16(&V[(size_t)sv0*128 + h*16], vf0);
    StBF16::ld16(&K[(size_t)sv1*128 + h*16], kf1);
    StBF16::ld16(&V[(size_t)sv1*128 + h*16], vf1);
    float a0 = 0.f, a1 = 0.f;
    #pragma unroll
    for (int i = 0; i < 16; ++i){ a0 += q[i]*kf0[i]; a1 += q[i]*kf1[i]; }
    float p0 = expf(a0*scale_h), p1 = expf(a1*scale_h);
    s += p0 + p1;
    #pragma unroll
    for (int i = 0; i < 16; ++i) acc[i] += p0*vf0[i] + p1*vf1[i];
  }
  if (j < e){
    int sv = slots[j];
    float kf[16], vf[16];
    StBF16::ld16(&K[(size_t)sv*128 + h*16], kf);
    StBF16::ld16(&V[(size_t)sv*128 + h*16], vf);
    float a = 0.f;
    #pragma unroll
    for (int i = 0; i < 16; ++i) a += q[i]*kf[i];
    float p = expf(a*scale_h);
    s += p;
    #pragma unroll
    for (int i = 0; i < 16; ++i) acc[i] += p*vf[i];
  }
  float inv = 1.f/(s + 1e-16f);
  #pragma unroll
  for (int i = 0; i < 16; ++i)
    QA[(size_t)n*128 + h*16 + i] = f2bf(acc[i]*inv);
}

struct Ptrs {
  const float *x_author, *x_paper, *win_w, *win_b, *kqv_w, *kqv_b, *a_w, *a_b;
  const float *skip, *rel_a, *rel_m, *rel_p, *out_w, *out_b;
  const int *src0, *dst0, *src1, *dst1;
};

static void run_pipeline(const Ptrs& P, float* d_out, char* ws, hipStream_t stream){
  using BF = unsigned short;
  size_t off = 0;
  auto alloc = [&](size_t bytes) -> void* {
    void* p = ws + off;
    off += (bytes + 255) & ~(size_t)255;
    return p;
  };
  BF* X0 = (BF*)alloc((size_t)Na*128*2);
  BF* X1 = (BF*)alloc((size_t)Np*128*2);
  BF* Q0 = (BF*)alloc((size_t)Na*128*2);   // Q -> agg in place
  BF* Q1 = (BF*)alloc((size_t)Np*128*2);
  BF* K0 = (BF*)alloc((size_t)Na*128*2);
  BF* K1 = (BF*)alloc((size_t)Np*128*2);
  BF* V0 = (BF*)alloc((size_t)Na*128*2);
  BF* V1 = (BF*)alloc((size_t)Np*128*2);
  float* effw = (float*)alloc((size_t)8*16384*4);
  float* effb = (float*)alloc((size_t)8*128*4);
  BF* wbf = (BF*)alloc((size_t)19*16384*2);
  int* rp0   = (int*)alloc((size_t)(Np+1)*4);
  int* cur0  = (int*)alloc((size_t)Np*4);
  int* slot0 = (int*)alloc((size_t)E*4);
  int* rp1   = (int*)alloc((size_t)(Na+1)*4);
  int* cur1  = (int*)alloc((size_t)Na*4);
  int* slot1 = (int*)alloc((size_t)E*4);
  int* bsum  = (int*)alloc((size_t)1024*4);

  auto cdiv = [](int a, int b){ return (a+b-1)/b; };
  const int geE = cdiv(E, 256);
  const int ga = cdiv(Na, 128), gp = cdiv(Np, 128);
  const int sb0 = cdiv(Np, SCAN_TILE), sb1 = cdiv(Na, SCAN_TILE);

  eff_w_kernel<<<512, 256, 0, stream>>>(P.kqv_w, P.kqv_b, P.rel_a, P.rel_m, effw, effb);

  // weight prep: slots 0-1 win, 2-5 Q(l,t), 6-9 K, 10-13 V, 14-17 a_w, 18 out_w
  PrepSrc ps;
  ps.s[0] = P.win_w; ps.s[1] = P.win_w + 16384;
  for (int l = 0; l < 2; ++l)
    for (int t = 0; t < 2; ++t){
      ps.s[2 + l*2 + t]  = P.kqv_w + (size_t)((l*2+t)*3+1)*16384;
      ps.s[6 + l*2 + t]  = effw + (size_t)(l*4+t*2+0)*16384;
      ps.s[10 + l*2 + t] = effw + (size_t)(l*4+t*2+1)*16384;
      ps.s[14 + l*2 + t] = P.a_w + (size_t)(l*2+t)*16384;
    }
  ps.s[18] = P.out_w;
  prep_w_kernel<<<cdiv(19*16384,256),256,0,stream>>>(ps, wbf);

  // ---- CSR build ----
  zero_int_kernel<<<512,256,0,stream>>>(cur0, Np);
  zero_int_kernel<<<512,256,0,stream>>>(cur1, Na);
  hist_kernel<<<geE,256,0,stream>>>(P.dst0, cur0, E);
  hist_kernel<<<geE,256,0,stream>>>(P.dst1, cur1, E);
  scan_a<<<sb0,256,0,stream>>>(cur0, bsum, Np);
  scan_b<<<1,1024,0,stream>>>(bsum, sb0);
  scan_c<<<sb0,256,0,stream>>>(cur0, bsum, rp0, Np);
  scan_a<<<sb1,256,0,stream>>>(cur1, bsum, Na);
  scan_b<<<1,1024,0,stream>>>(bsum, sb1);
  scan_c<<<sb1,256,0,stream>>>(cur1, bsum, rp1, Na);
  fill_slots_kernel<<<geE,256,0,stream>>>(P.src0, P.dst0, cur0, slot0, E);
  fill_slots_kernel<<<geE,256,0,stream>>>(P.src1, P.dst1, cur1, slot1, E);

  auto W = [&](int s){ return wbf + (size_t)s*16384; };

  // input projections + relu (fp32 in, bf16 out) — merged pair
  {
    GemmArgs g{};
    g.X[0] = P.x_author; g.X[1] = P.x_paper;
    g.WT[0] = W(0); g.WT[1] = W(1);
    g.bias[0] = P.win_b; g.bias[1] = P.win_b + 128;
    g.Y[0] = X0; g.Y[1] = X1;
    g.N[0] = Na; g.N[1] = Np; g.blocks0 = ga;
    gemm_kernel<128,0,1,0,StF32><<<ga+gp,512,0,stream>>>(g);
  }

  const int ab0 = cdiv(Np*8,256), ab1 = cdiv(Na*8,256);

  for (int l = 0; l < L; ++l){
    QkvArgs q{};
    q.X[0] = X0; q.X[1] = X1;
    for (int t2 = 0; t2 < 2; ++t2){
      q.WT[t2][0] = W(2+l*2+t2); q.WT[t2][1] = W(6+l*2+t2); q.WT[t2][2] = W(10+l*2+t2);
      q.bias[t2][0] = P.kqv_b + ((l*2+t2)*3+1)*128;
      q.bias[t2][1] = effb + (l*4+t2*2+0)*128;
      q.bias[t2][2] = effb + (l*4+t2*2+1)*128;
    }
    q.out[0][0] = Q0; q.out[0][1] = K0; q.out[0][2] = V0;
    q.out[1][0] = Q1; q.out[1][1] = K1; q.out[1][2] = V1;
    q.N[0] = Na; q.N[1] = Np; q.blocks0 = ga;
    qkv_kernel<<<ga+gp,512,0,stream>>>(q);

    AttnArgs a{};
    a.QA[0] = Q1; a.K[0] = K0; a.V[0] = V0; a.rp[0] = rp0; a.slots[0] = slot0;
    a.relp[0] = P.rel_p + (l*2+0)*8; a.N[0] = Np;
    a.QA[1] = Q0; a.K[1] = K1; a.V[1] = V1; a.rp[1] = rp1; a.slots[1] = slot1;
    a.relp[1] = P.rel_p + (l*2+1)*8; a.N[1] = Na;
    a.blocks0 = ab0;
    attn_gather_kernel<<<ab0+ab1,256,0,stream>>>(a);

    GemmArgs g{};
    g.X[0] = Q0; g.X[1] = Q1;
    g.WT[0] = W(14+l*2+0); g.WT[1] = W(14+l*2+1);
    g.bias[0] = P.a_b + (l*2+0)*128; g.bias[1] = P.a_b + (l*2+1)*128;
    g.Y[0] = X0; g.Y[1] = X1;
    g.skip_x[0] = X0; g.skip_x[1] = X1;
    g.skip_s[0] = P.skip + (l*2+0); g.skip_s[1] = P.skip + (l*2+1);
    g.N[0] = Na; g.N[1] = Np; g.blocks0 = ga;
    gemm_kernel<128,1,0,1,StBF16><<<ga+gp,512,0,stream>>>(g);
  }

  {
    GemmArgs g{};
    g.X[0] = X0; g.X[1] = nullptr;
    g.WT[0] = W(18); g.WT[1] = nullptr;
    g.bias[0] = P.out_b; g.bias[1] = nullptr;
    g.Y[0] = d_out; g.Y[1] = nullptr;
    g.N[0] = Na; g.N[1] = 0; g.blocks0 = ga;
    gemm_kernel<64,0,0,0,StBF16><<<ga,512,0,stream>>>(g);
  }
}

static size_t plan_bytes(){
  auto al = [](size_t x){ return (x + 255) & ~(size_t)255; };
  size_t t = 0;
  t += 4*(al((size_t)Na*128*2) + al((size_t)Np*128*2));   // X,Q,K,V bf16
  t += al((size_t)8*16384*4) + al((size_t)8*128*4) + al((size_t)19*16384*2);
  t += al((size_t)(Np+1)*4) + al((size_t)Np*4) + al((size_t)E*4);
  t += al((size_t)(Na+1)*4) + al((size_t)Na*4) + al((size_t)E*4);
  t += al((size_t)1024*4);
  return t;
}

} // namespace

extern "C" void kernel_launch(void* const* d_in, const int* in_sizes, int n_in,
                              void* d_out, int out_size, void* d_ws, size_t ws_size,
                              hipStream_t stream){
  Ptrs P;
  P.x_author = (const float*)d_in[0];
  P.x_paper  = (const float*)d_in[1];
  P.win_w = (const float*)d_in[2];
  P.win_b = (const float*)d_in[3];
  P.kqv_w = (const float*)d_in[4];
  P.kqv_b = (const float*)d_in[5];
  P.a_w   = (const float*)d_in[6];
  P.a_b   = (const float*)d_in[7];
  P.skip  = (const float*)d_in[8];
  P.rel_a = (const float*)d_in[9];
  P.rel_m = (const float*)d_in[10];
  P.rel_p = (const float*)d_in[11];
  P.out_w = (const float*)d_in[12];
  P.out_b = (const float*)d_in[13];
  P.src0 = (const int*)d_in[14];
  P.dst0 = (const int*)d_in[15];
  P.src1 = (const int*)d_in[16];
  P.dst1 = (const int*)d_in[17];

  if (ws_size >= plan_bytes()){
    run_pipeline(P, (float*)d_out, (char*)d_ws, stream);
  } else {
    diag_kernel<<<1,1,0,stream>>>((float*)d_out, (float)((double)ws_size/1.0e6));
  }
}

// Round 15
// 331.253 us; speedup vs baseline: 1.1715x; 1.0218x over previous
//
#include <hip/hip_runtime.h>
#include <math.h>

namespace {

constexpr int Na = 50000, Np = 100000, L = 2, E = 150000;
constexpr int SCAN_TILE = 2048;

typedef __attribute__((ext_vector_type(8))) short short8v;
typedef __attribute__((ext_vector_type(4))) float f32x4;

__device__ inline float geluf(float x){ return 0.5f*x*(1.0f + erff(x*0.7071067811865476f)); }

__device__ inline float bf2f(unsigned short u){ return __uint_as_float(((unsigned)u) << 16); }
__device__ inline unsigned short f2bf(float f){
  unsigned u = __float_as_uint(f);
  u += 0x7FFFu + ((u >> 16) & 1u);   // round-to-nearest-even
  return (unsigned short)(u >> 16);
}
__device__ inline unsigned pk2(float a, float b){
  return (unsigned)f2bf(a) | ((unsigned)f2bf(b) << 16);
}

struct StF32 {
  using T = float;
  static __device__ short8v ld8(const T* __restrict__ p){
    float4 lo = *reinterpret_cast<const float4*>(p);
    float4 hi = *reinterpret_cast<const float4*>(p+4);
    short8v v;
    v[0]=(short)f2bf(lo.x); v[1]=(short)f2bf(lo.y); v[2]=(short)f2bf(lo.z); v[3]=(short)f2bf(lo.w);
    v[4]=(short)f2bf(hi.x); v[5]=(short)f2bf(hi.y); v[6]=(short)f2bf(hi.z); v[7]=(short)f2bf(hi.w);
    return v;
  }
};
struct StBF16 {
  using T = unsigned short;
  static __device__ short8v ld8(const T* __restrict__ p){
    return *reinterpret_cast<const short8v*>(p);
  }
  static __device__ void ld8f(const T* __restrict__ p, float* o){
    uint4 u = *reinterpret_cast<const uint4*>(p);
    o[0] = bf2f((unsigned short)(u.x & 0xffff));
    o[1] = bf2f((unsigned short)(u.x >> 16));
    o[2] = bf2f((unsigned short)(u.y & 0xffff));
    o[3] = bf2f((unsigned short)(u.y >> 16));
    o[4] = bf2f((unsigned short)(u.z & 0xffff));
    o[5] = bf2f((unsigned short)(u.z >> 16));
    o[6] = bf2f((unsigned short)(u.w & 0xffff));
    o[7] = bf2f((unsigned short)(u.w >> 16));
  }
};

__global__ void zero_int_kernel(int* __restrict__ p, int n){
  int i = blockIdx.x*256 + threadIdx.x;
  int stride = gridDim.x*256;
  for (; i < n; i += stride) p[i] = 0;
}

__global__ void diag_kernel(float* o, float v){
  if (threadIdx.x == 0 && blockIdx.x == 0) o[0] = v;
}

__global__ void hist_kernel(const int* __restrict__ dst, int* __restrict__ counts, int nE){
  int e = blockIdx.x*256 + threadIdx.x;
  if (e >= nE) return;
  atomicAdd(&counts[dst[e]], 1);
}

// ---- multi-block exclusive scan (3 phases) ----
__global__ void scan_a(const int* __restrict__ counts, int* __restrict__ bsum, int n){
  int base = blockIdx.x*SCAN_TILE;
  int s = 0;
  for (int i = threadIdx.x; i < SCAN_TILE; i += 256){
    int g = base + i;
    s += (g < n) ? counts[g] : 0;
  }
  __shared__ int red[256];
  red[threadIdx.x] = s;
  __syncthreads();
  for (int off = 128; off > 0; off >>= 1){
    if (threadIdx.x < off) red[threadIdx.x] += red[threadIdx.x + off];
    __syncthreads();
  }
  if (threadIdx.x == 0) bsum[blockIdx.x] = red[0];
}

__global__ void scan_b(int* __restrict__ bsum, int nb){
  __shared__ int sh[1024];
  int t = threadIdx.x;
  int v = (t < nb) ? bsum[t] : 0;
  sh[t] = v;
  __syncthreads();
  for (int off = 1; off < 1024; off <<= 1){
    int add = (t >= off) ? sh[t-off] : 0;
    __syncthreads();
    sh[t] += add;
    __syncthreads();
  }
  if (t < nb) bsum[t] = sh[t] - v;   // exclusive
}

__global__ void scan_c(int* __restrict__ counts, const int* __restrict__ bsum,
                       int* __restrict__ rp, int n){
  int base = blockIdx.x*SCAN_TILE;
  __shared__ int sh[SCAN_TILE];
  for (int i = threadIdx.x; i < SCAN_TILE; i += 256){
    int g = base + i;
    sh[i] = (g < n) ? counts[g] : 0;
  }
  __syncthreads();
  int t = threadIdx.x;
  int loc[8], s = 0;
  #pragma unroll
  for (int i = 0; i < 8; ++i){ loc[i] = s; s += sh[t*8 + i]; }
  __shared__ int red[256];
  red[t] = s;
  __syncthreads();
  for (int off = 1; off < 256; off <<= 1){
    int add = (t >= off) ? red[t-off] : 0;
    __syncthreads();
    red[t] += add;
    __syncthreads();
  }
  int texcl = red[t] - s + bsum[blockIdx.x];
  #pragma unroll
  for (int i = 0; i < 8; ++i){
    int g = base + t*8 + i;
    if (g < n){
      int v = texcl + loc[i];
      rp[g] = v;
      counts[g] = v;           // cursor for fill pass
      if (g == n-1) rp[n] = v + sh[t*8 + i];
    }
  }
}

__global__ void fill_slots_kernel(const int* __restrict__ src, const int* __restrict__ dst,
                                  int* __restrict__ cursor, int* __restrict__ slots, int nE){
  int e = blockIdx.x*256 + threadIdx.x;
  if (e >= nE) return;
  int slot = atomicAdd(&cursor[dst[e]], 1);
  slots[slot] = src[e];
}

// Fold rel_a/rel_m into K/V projection weights (fp32).
__global__ void eff_w_kernel(const float* __restrict__ kqv_w, const float* __restrict__ kqv_b,
                             const float* __restrict__ rel_a, const float* __restrict__ rel_m,
                             float* __restrict__ effw, float* __restrict__ effb){
  int idx = blockIdx.x*256 + threadIdx.x;
  if (idx >= 2*2*2*128*128) return;
  int j = idx & 127; int f = (idx >> 7) & 127; int c = idx >> 14;
  int kv = c & 1, t = (c >> 1) & 1, l = c >> 2;
  int h = j >> 4, e2 = j & 15;
  int i = (kv == 0) ? 0 : 2;  // K uses i=0, V uses i=2
  const float* W = kqv_w + ((size_t)(((l*2 + t)*3 + i)*128) + f)*128 + h*16;
  const float* A = ((kv == 0) ? rel_a : rel_m) + ((size_t)(l*2 + t)*8 + h)*256;
  float acc = 0.f;
  #pragma unroll
  for (int d = 0; d < 16; ++d) acc += W[d]*A[d*16 + e2];
  effw[(size_t)c*16384 + f*128 + j] = acc;
  if (f == 0){
    const float* B = kqv_b + (size_t)((l*2 + t)*3 + i)*128 + h*16;
    float ab = 0.f;
    #pragma unroll
    for (int d = 0; d < 16; ++d) ab += B[d]*A[d*16 + e2];
    effb[c*128 + j] = ab;
  }
}

// Convert 19 weight matrices fp32 [k][n] -> bf16 transposed [n][128(k)].
struct PrepSrc { const float* s[19]; };
__global__ void prep_w_kernel(PrepSrc P, unsigned short* __restrict__ wbf){
  int idx = blockIdx.x*256 + threadIdx.x;
  if (idx >= 19*16384) return;
  int s = idx >> 14, j = idx & 16383;
  int n = j >> 7, k = j & 127;
  int nc = (s == 18) ? 64 : 128;
  if (n >= nc) return;
  wbf[(size_t)s*16384 + n*128 + k] = f2bf(P.s[s][(size_t)k*nc + n]);
}

// Stage bf16 WT [rows][128] into LDS with 16B-chunk XOR swizzle (512-thread).
__device__ inline void stage_w(short* Bs, const unsigned short* __restrict__ WT, int t, int rows){
  for (int c = t; c < rows*16; c += 512){
    int r = c >> 4, c16 = c & 15;
    short8v v = *reinterpret_cast<const short8v*>(&WT[r*128 + c16*8]);
    *reinterpret_cast<short8v*>(&Bs[r*128 + ((c16 ^ (r&7))<<3)]) = v;
  }
}

struct GemmArgs {
  const void* X[2];
  const unsigned short* WT[2];
  const float* bias[2];
  void* Y[2];
  const unsigned short* skip_x[2];
  const float* skip_s[2];
  int N[2];
  int blocks0;
};

// MFMA GEMM (512 threads, 8 waves 2x4): Y[N,BN] = epi( act(X[N,128]) @ W + bias ).
// Swapped-operand MFMA -> lane holds 4 consecutive output cols; repack via LDS -> 16B stores.
template<int BN, int GELU_IN, int RELU_OUT, int SKIP, typename SIn>
__global__ __launch_bounds__(512) void gemm_kernel(GemmArgs Ar)
{
  __shared__ __align__(16) short As[128*128];
  __shared__ __align__(16) char Braw[32768];
  short* Bs = (short*)Braw;
  const int t = threadIdx.x;
  const int part = (blockIdx.x < Ar.blocks0) ? 0 : 1;
  const int bid = part ? (blockIdx.x - Ar.blocks0) : blockIdx.x;
  const typename SIn::T* X = (const typename SIn::T*)Ar.X[part];
  const unsigned short* WT = Ar.WT[part];
  const float* bias = Ar.bias[part];
  const int N = Ar.N[part];
  const int row0 = bid*128;
  for (int c = t; c < 2048; c += 512){
    int r = c >> 4, c16 = c & 15;
    int gr = row0 + r;
    short8v v;
    if (gr < N){
      v = SIn::ld8(&X[(size_t)gr*128 + c16*8]);
      if (GELU_IN){
        #pragma unroll
        for (int i = 0; i < 8; ++i){
          float f = geluf(bf2f((unsigned short)v[i]));
          v[i] = (short)f2bf(f);
        }
      }
    } else {
      v = (short8v)0;
    }
    *reinterpret_cast<short8v*>(&As[r*128 + ((c16 ^ (r&7))<<3)]) = v;
  }
  stage_w(Bs, WT, t, BN);
  __syncthreads();
  const int lane = t & 63, wid = t >> 6;
  const int wm = wid >> 2, wn = wid & 3;       // 2 x 4 waves
  constexpr int NR = BN/64;
  const int lr = lane & 15, lk = lane >> 4;
  f32x4 acc[4][NR] = {};
  #pragma unroll
  for (int kk = 0; kk < 4; ++kk){
    int kc = kk*4 + lk;
    short8v a[4], b[NR];
    #pragma unroll
    for (int m = 0; m < 4; ++m){
      int r = wm*64 + m*16 + lr;
      a[m] = *reinterpret_cast<const short8v*>(&As[r*128 + ((kc ^ (r&7))<<3)]);
    }
    #pragma unroll
    for (int n = 0; n < NR; ++n){
      int col = wn*(BN/4) + n*16 + lr;
      b[n] = *reinterpret_cast<const short8v*>(&Bs[col*128 + ((kc ^ (col&7))<<3)]);
    }
    #pragma unroll
    for (int m = 0; m < 4; ++m)
      #pragma unroll
      for (int n = 0; n < NR; ++n)
        acc[m][n] = __builtin_amdgcn_mfma_f32_16x16x32_bf16(b[n], a[m], acc[m][n], 0, 0, 0);
  }
  __syncthreads();   // Bs weight reads done -> reuse as repack buffer

  if constexpr (BN == 128){
    #pragma unroll
    for (int m = 0; m < 4; ++m){
      int row = wm*64 + m*16 + lr;
      #pragma unroll
      for (int n = 0; n < NR; ++n){
        int col0 = wn*32 + n*16 + lk*4;
        float4 b4 = *reinterpret_cast<const float4*>(&bias[col0]);
        float y0 = acc[m][n][0] + b4.x, y1 = acc[m][n][1] + b4.y;
        float y2 = acc[m][n][2] + b4.z, y3 = acc[m][n][3] + b4.w;
        if (RELU_OUT){
          y0 = fmaxf(y0,0.f); y1 = fmaxf(y1,0.f); y2 = fmaxf(y2,0.f); y3 = fmaxf(y3,0.f);
        }
        uint2 pk; pk.x = pk2(y0,y1); pk.y = pk2(y2,y3);
        int c16 = col0 >> 3;
        *reinterpret_cast<uint2*>(&Bs[row*128 + ((c16 ^ (row&7))<<3) + (col0&7)]) = pk;
      }
    }
    __syncthreads();
    float g = 1.f, og = 0.f;
    if (SKIP){ float sv = *Ar.skip_s[part]; g = 1.f/(1.f + expf(-sv)); og = 1.f - g; }
    unsigned short* out = (unsigned short*)Ar.Y[part];
    const unsigned short* skip_x = Ar.skip_x[part];
    for (int c = t; c < 2048; c += 512){
      int r = c >> 4, c16 = c & 15;
      int gr = row0 + r;
      if (gr >= N) continue;
      short8v v = *reinterpret_cast<const short8v*>(&Bs[r*128 + ((c16 ^ (r&7))<<3)]);
      if (SKIP){
        short8v s8 = *reinterpret_cast<const short8v*>(&skip_x[(size_t)gr*128 + c16*8]);
        short8v o8;
        #pragma unroll
        for (int i = 0; i < 8; ++i)
          o8[i] = (short)f2bf(g*bf2f((unsigned short)v[i]) + og*bf2f((unsigned short)s8[i]));
        *reinterpret_cast<short8v*>(&out[(size_t)gr*128 + c16*8]) = o8;
      } else {
        *reinterpret_cast<short8v*>(&out[(size_t)gr*128 + c16*8]) = v;
      }
    }
  } else {
    // BN==64: fp32 repack (32 KB), fp32 coalesced out (classifier)
    float* Bf = (float*)Braw;
    #pragma unroll
    for (int m = 0; m < 4; ++m){
      int row = wm*64 + m*16 + lr;
      int col0 = wn*16 + lk*4;
      float4 b4 = *reinterpret_cast<const float4*>(&bias[col0]);
      float4 y;
      y.x = acc[m][0][0] + b4.x; y.y = acc[m][0][1] + b4.y;
      y.z = acc[m][0][2] + b4.z; y.w = acc[m][0][3] + b4.w;
      int cf = col0 >> 2;
      *reinterpret_cast<float4*>(&Bf[row*64 + ((cf ^ (row&7))<<2)]) = y;
    }
    __syncthreads();
    float* out = (float*)Ar.Y[part];
    for (int c = t; c < 2048; c += 512){
      int r = c >> 4, cf = c & 15;
      int gr = row0 + r;
      if (gr >= N) continue;
      float4 v = *reinterpret_cast<const float4*>(&Bf[r*64 + ((cf ^ (r&7))<<2)]);
      *reinterpret_cast<float4*>(&out[(size_t)gr*64 + cf*4]) = v;
    }
  }
}

struct QkvArgs {
  const unsigned short* X[2];
  const unsigned short* WT[2][3];
  const float* bias[2][3];
  unsigned short* out[2][3];   // Q, K, V
  int N[2];
  int blocks0;
};

// Fused QKV (512 threads, 64-row tiles): As 16K + Bs 32K + Rs 16K = 64 KB (2 blocks/CU).
// Per weight: MFMA -> repack Rs -> barrier -> [stage B(s+1) || readout Rs] -> barrier.
__global__ __launch_bounds__(512) void qkv_kernel(QkvArgs Ar)
{
  __shared__ __align__(16) short As[64*128];
  __shared__ __align__(16) short Bs[128*128];
  __shared__ __align__(16) short Rs[64*128];
  const int t = threadIdx.x;
  const int part = (blockIdx.x < Ar.blocks0) ? 0 : 1;
  const int bid = part ? (blockIdx.x - Ar.blocks0) : blockIdx.x;
  const unsigned short* X = Ar.X[part];
  const int N = Ar.N[part];
  const int row0 = bid*64;
  for (int c = t; c < 1024; c += 512){
    int r = c >> 4, c16 = c & 15;
    int gr = row0 + r;
    short8v v = (gr < N) ? *reinterpret_cast<const short8v*>(&X[(size_t)gr*128 + c16*8])
                         : (short8v)0;
    *reinterpret_cast<short8v*>(&As[r*128 + ((c16 ^ (r&7))<<3)]) = v;
  }
  stage_w(Bs, Ar.WT[part][0], t, 128);
  __syncthreads();
  const int lane = t & 63, wid = t >> 6;
  const int wm = wid >> 2, wn = wid & 3;       // 2 x 4 waves; wave tile 32 rows x 32 cols
  const int lr = lane & 15, lk = lane >> 4;
  #pragma unroll
  for (int s = 0; s < 3; ++s){
    f32x4 acc[2][2] = {};
    #pragma unroll
    for (int kk = 0; kk < 4; ++kk){
      int kc = kk*4 + lk;
      short8v a[2], b[2];
      #pragma unroll
      for (int m = 0; m < 2; ++m){
        int r = wm*32 + m*16 + lr;
        a[m] = *reinterpret_cast<const short8v*>(&As[r*128 + ((kc ^ (r&7))<<3)]);
      }
      #pragma unroll
      for (int n = 0; n < 2; ++n){
        int col = wn*32 + n*16 + lr;
        b[n] = *reinterpret_cast<const short8v*>(&Bs[col*128 + ((kc ^ (col&7))<<3)]);
      }
      #pragma unroll
      for (int m = 0; m < 2; ++m)
        #pragma unroll
        for (int n = 0; n < 2; ++n)
          acc[m][n] = __builtin_amdgcn_mfma_f32_16x16x32_bf16(b[n], a[m], acc[m][n], 0, 0, 0);
    }
    // repack to Rs (disjoint buffer -> no barrier needed before writes)
    const float* bi = Ar.bias[part][s];
    #pragma unroll
    for (int m = 0; m < 2; ++m){
      int row = wm*32 + m*16 + lr;
      #pragma unroll
      for (int n = 0; n < 2; ++n){
        int col0 = wn*32 + n*16 + lk*4;
        float4 b4 = *reinterpret_cast<const float4*>(&bi[col0]);
        uint2 pk;
        pk.x = pk2(acc[m][n][0] + b4.x, acc[m][n][1] + b4.y);
        pk.y = pk2(acc[m][n][2] + b4.z, acc[m][n][3] + b4.w);
        int c16 = col0 >> 3;
        *reinterpret_cast<uint2*>(&Rs[row*128 + ((c16 ^ (row&7))<<3) + (col0&7)]) = pk;
      }
    }
    __syncthreads();   // all MFMA reads of Bs done; Rs complete
    if (s < 2) stage_w(Bs, Ar.WT[part][s+1], t, 128);   // overlap with readout
    unsigned short* out = Ar.out[part][s];
    for (int c = t; c < 1024; c += 512){
      int r = c >> 4, c16 = c & 15;
      int gr = row0 + r;
      if (gr >= N) continue;
      short8v v = *reinterpret_cast<const short8v*>(&Rs[r*128 + ((c16 ^ (r&7))<<3)]);
      *reinterpret_cast<short8v*>(&out[(size_t)gr*128 + c16*8]) = v;
    }
    __syncthreads();   // Bs staged + Rs readout done
  }
}

struct AttnArgs {
  unsigned short* QA[2];
  const unsigned short* K[2];
  const unsigned short* V[2];
  const int* rp[2];
  const int* slots[2];
  const float* relp[2];
  int N[2];
  int blocks0;
};

// Fused attention, half-head granularity: thread per (node, head, half-of-16).
// Full 16-dot completed via __shfl_xor(lane^1). No-max softmax. Unroll x2.
__global__ void attn_gather_kernel(AttnArgs Ar){
  const int part = (blockIdx.x < Ar.blocks0) ? 0 : 1;
  const int bid = part ? (blockIdx.x - Ar.blocks0) : blockIdx.x;
  int idx = bid*256 + threadIdx.x;
  const int N = Ar.N[part];
  if (idx >= N*16) return;
  int th = idx & 15, n = idx >> 4;
  int h = th >> 1, half = th & 1;
  unsigned short* QA = Ar.QA[part];
  const unsigned short* K = Ar.K[part];
  const unsigned short* V = Ar.V[part];
  const int off16 = h*16 + half*8;
  float q[8];
  StBF16::ld8f(&QA[(size_t)n*128 + off16], q);
  float scale_h = Ar.relp[part][h]*0.25f;
  float s = 0.f, acc[8];
  #pragma unroll
  for (int i = 0; i < 8; ++i) acc[i] = 0.f;
  int b = Ar.rp[part][n], e = Ar.rp[part][n+1];
  const int* slots = Ar.slots[part];
  int j = b;
  for (; j + 2 <= e; j += 2){
    int sv0 = slots[j], sv1 = slots[j+1];
    float kf0[8], vf0[8], kf1[8], vf1[8];
    StBF16::ld8f(&K[(size_t)sv0*128 + off16], kf0);
    StBF16::ld8f(&V[(size_t)sv0*128 + off16], vf0);
    StBF16::ld8f(&K[(size_t)sv1*128 + off16], kf1);
    StBF16::ld8f(&V[(size_t)sv1*128 + off16], vf1);
    float a0 = 0.f, a1 = 0.f;
    #pragma unroll
    for (int i = 0; i < 8; ++i){ a0 += q[i]*kf0[i]; a1 += q[i]*kf1[i]; }
    a0 += __shfl_xor(a0, 1);
    a1 += __shfl_xor(a1, 1);
    float p0 = expf(a0*scale_h), p1 = expf(a1*scale_h);
    s += p0 + p1;
    #pragma unroll
    for (int i = 0; i < 8; ++i) acc[i] += p0*vf0[i] + p1*vf1[i];
  }
  if (j < e){
    int sv = slots[j];
    float kf[8], vf[8];
    StBF16::ld8f(&K[(size_t)sv*128 + off16], kf);
    StBF16::ld8f(&V[(size_t)sv*128 + off16], vf);
    float a = 0.f;
    #pragma unroll
    for (int i = 0; i < 8; ++i) a += q[i]*kf[i];
    a += __shfl_xor(a, 1);
    float p = expf(a*scale_h);
    s += p;
    #pragma unroll
    for (int i = 0; i < 8; ++i) acc[i] += p*vf[i];
  }
  float inv = 1.f/(s + 1e-16f);
  uint4 o;
  o.x = pk2(acc[0]*inv, acc[1]*inv);
  o.y = pk2(acc[2]*inv, acc[3]*inv);
  o.z = pk2(acc[4]*inv, acc[5]*inv);
  o.w = pk2(acc[6]*inv, acc[7]*inv);
  *reinterpret_cast<uint4*>(&QA[(size_t)n*128 + off16]) = o;
}

struct Ptrs {
  const float *x_author, *x_paper, *win_w, *win_b, *kqv_w, *kqv_b, *a_w, *a_b;
  const float *skip, *rel_a, *rel_m, *rel_p, *out_w, *out_b;
  const int *src0, *dst0, *src1, *dst1;
};

static void run_pipeline(const Ptrs& P, float* d_out, char* ws, hipStream_t stream){
  using BF = unsigned short;
  size_t off = 0;
  auto alloc = [&](size_t bytes) -> void* {
    void* p = ws + off;
    off += (bytes + 255) & ~(size_t)255;
    return p;
  };
  BF* X0 = (BF*)alloc((size_t)Na*128*2);
  BF* X1 = (BF*)alloc((size_t)Np*128*2);
  BF* Q0 = (BF*)alloc((size_t)Na*128*2);   // Q -> agg in place
  BF* Q1 = (BF*)alloc((size_t)Np*128*2);
  BF* K0 = (BF*)alloc((size_t)Na*128*2);
  BF* K1 = (BF*)alloc((size_t)Np*128*2);
  BF* V0 = (BF*)alloc((size_t)Na*128*2);
  BF* V1 = (BF*)alloc((size_t)Np*128*2);
  float* effw = (float*)alloc((size_t)8*16384*4);
  float* effb = (float*)alloc((size_t)8*128*4);
  BF* wbf = (BF*)alloc((size_t)19*16384*2);
  int* rp0   = (int*)alloc((size_t)(Np+1)*4);
  int* cur0  = (int*)alloc((size_t)Np*4);
  int* slot0 = (int*)alloc((size_t)E*4);
  int* rp1   = (int*)alloc((size_t)(Na+1)*4);
  int* cur1  = (int*)alloc((size_t)Na*4);
  int* slot1 = (int*)alloc((size_t)E*4);
  int* bsum  = (int*)alloc((size_t)1024*4);

  auto cdiv = [](int a, int b){ return (a+b-1)/b; };
  const int geE = cdiv(E, 256);
  const int ga = cdiv(Na, 128), gp = cdiv(Np, 128);
  const int qa = cdiv(Na, 64), qp = cdiv(Np, 64);
  const int sb0 = cdiv(Np, SCAN_TILE), sb1 = cdiv(Na, SCAN_TILE);

  eff_w_kernel<<<512, 256, 0, stream>>>(P.kqv_w, P.kqv_b, P.rel_a, P.rel_m, effw, effb);

  // weight prep: slots 0-1 win, 2-5 Q(l,t), 6-9 K, 10-13 V, 14-17 a_w, 18 out_w
  PrepSrc ps;
  ps.s[0] = P.win_w; ps.s[1] = P.win_w + 16384;
  for (int l = 0; l < 2; ++l)
    for (int t = 0; t < 2; ++t){
      ps.s[2 + l*2 + t]  = P.kqv_w + (size_t)((l*2+t)*3+1)*16384;
      ps.s[6 + l*2 + t]  = effw + (size_t)(l*4+t*2+0)*16384;
      ps.s[10 + l*2 + t] = effw + (size_t)(l*4+t*2+1)*16384;
      ps.s[14 + l*2 + t] = P.a_w + (size_t)(l*2+t)*16384;
    }
  ps.s[18] = P.out_w;
  prep_w_kernel<<<cdiv(19*16384,256),256,0,stream>>>(ps, wbf);

  // ---- CSR build ----
  zero_int_kernel<<<512,256,0,stream>>>(cur0, Np);
  zero_int_kernel<<<512,256,0,stream>>>(cur1, Na);
  hist_kernel<<<geE,256,0,stream>>>(P.dst0, cur0, E);
  hist_kernel<<<geE,256,0,stream>>>(P.dst1, cur1, E);
  scan_a<<<sb0,256,0,stream>>>(cur0, bsum, Np);
  scan_b<<<1,1024,0,stream>>>(bsum, sb0);
  scan_c<<<sb0,256,0,stream>>>(cur0, bsum, rp0, Np);
  scan_a<<<sb1,256,0,stream>>>(cur1, bsum, Na);
  scan_b<<<1,1024,0,stream>>>(bsum, sb1);
  scan_c<<<sb1,256,0,stream>>>(cur1, bsum, rp1, Na);
  fill_slots_kernel<<<geE,256,0,stream>>>(P.src0, P.dst0, cur0, slot0, E);
  fill_slots_kernel<<<geE,256,0,stream>>>(P.src1, P.dst1, cur1, slot1, E);

  auto W = [&](int s){ return wbf + (size_t)s*16384; };

  // input projections + relu (fp32 in, bf16 out) — merged pair
  {
    GemmArgs g{};
    g.X[0] = P.x_author; g.X[1] = P.x_paper;
    g.WT[0] = W(0); g.WT[1] = W(1);
    g.bias[0] = P.win_b; g.bias[1] = P.win_b + 128;
    g.Y[0] = X0; g.Y[1] = X1;
    g.N[0] = Na; g.N[1] = Np; g.blocks0 = ga;
    gemm_kernel<128,0,1,0,StF32><<<ga+gp,512,0,stream>>>(g);
  }

  const int ab0 = cdiv(Np*16,256), ab1 = cdiv(Na*16,256);

  for (int l = 0; l < L; ++l){
    QkvArgs q{};
    q.X[0] = X0; q.X[1] = X1;
    for (int t2 = 0; t2 < 2; ++t2){
      q.WT[t2][0] = W(2+l*2+t2); q.WT[t2][1] = W(6+l*2+t2); q.WT[t2][2] = W(10+l*2+t2);
      q.bias[t2][0] = P.kqv_b + ((l*2+t2)*3+1)*128;
      q.bias[t2][1] = effb + (l*4+t2*2+0)*128;
      q.bias[t2][2] = effb + (l*4+t2*2+1)*128;
    }
    q.out[0][0] = Q0; q.out[0][1] = K0; q.out[0][2] = V0;
    q.out[1][0] = Q1; q.out[1][1] = K1; q.out[1][2] = V1;
    q.N[0] = Na; q.N[1] = Np; q.blocks0 = qa;
    qkv_kernel<<<qa+qp,512,0,stream>>>(q);

    AttnArgs a{};
    a.QA[0] = Q1; a.K[0] = K0; a.V[0] = V0; a.rp[0] = rp0; a.slots[0] = slot0;
    a.relp[0] = P.rel_p + (l*2+0)*8; a.N[0] = Np;
    a.QA[1] = Q0; a.K[1] = K1; a.V[1] = V1; a.rp[1] = rp1; a.slots[1] = slot1;
    a.relp[1] = P.rel_p + (l*2+1)*8; a.N[1] = Na;
    a.blocks0 = ab0;
    attn_gather_kernel<<<ab0+ab1,256,0,stream>>>(a);

    GemmArgs g{};
    g.X[0] = Q0; g.X[1] = Q1;
    g.WT[0] = W(14+l*2+0); g.WT[1] = W(14+l*2+1);
    g.bias[0] = P.a_b + (l*2+0)*128; g.bias[1] = P.a_b + (l*2+1)*128;
    g.Y[0] = X0; g.Y[1] = X1;
    g.skip_x[0] = X0; g.skip_x[1] = X1;
    g.skip_s[0] = P.skip + (l*2+0); g.skip_s[1] = P.skip + (l*2+1);
    g.N[0] = Na; g.N[1] = Np; g.blocks0 = ga;
    gemm_kernel<128,1,0,1,StBF16><<<ga+gp,512,0,stream>>>(g);
  }

  {
    GemmArgs g{};
    g.X[0] = X0; g.X[1] = nullptr;
    g.WT[0] = W(18); g.WT[1] = nullptr;
    g.bias[0] = P.out_b; g.bias[1] = nullptr;
    g.Y[0] = d_out; g.Y[1] = nullptr;
    g.N[0] = Na; g.N[1] = 0; g.blocks0 = ga;
    gemm_kernel<64,0,0,0,StBF16><<<ga,512,0,stream>>>(g);
  }
}

static size_t plan_bytes(){
  auto al = [](size_t x){ return (x + 255) & ~(size_t)255; };
  size_t t = 0;
  t += 4*(al((size_t)Na*128*2) + al((size_t)Np*128*2));   // X,Q,K,V bf16
  t += al((size_t)8*16384*4) + al((size_t)8*128*4) + al((size_t)19*16384*2);
  t += al((size_t)(Np+1)*4) + al((size_t)Np*4) + al((size_t)E*4);
  t += al((size_t)(Na+1)*4) + al((size_t)Na*4) + al((size_t)E*4);
  t += al((size_t)1024*4);
  return t;
}

} // namespace

extern "C" void kernel_launch(void* const* d_in, const int* in_sizes, int n_in,
                              void* d_out, int out_size, void* d_ws, size_t ws_size,
                              hipStream_t stream){
  Ptrs P;
  P.x_author = (const float*)d_in[0];
  P.x_paper  = (const float*)d_in[1];
  P.win_w = (const float*)d_in[2];
  P.win_b = (const float*)d_in[3];
  P.kqv_w = (const float*)d_in[4];
  P.kqv_b = (const float*)d_in[5];
  P.a_w   = (const float*)d_in[6];
  P.a_b   = (const float*)d_in[7];
  P.skip  = (const float*)d_in[8];
  P.rel_a = (const float*)d_in[9];
  P.rel_m = (const float*)d_in[10];
  P.rel_p = (const float*)d_in[11];
  P.out_w = (const float*)d_in[12];
  P.out_b = (const float*)d_in[13];
  P.src0 = (const int*)d_in[14];
  P.dst0 = (const int*)d_in[15];
  P.src1 = (const int*)d_in[16];
  P.dst1 = (const int*)d_in[17];

  if (ws_size >= plan_bytes()){
    run_pipeline(P, (float*)d_out, (char*)d_ws, stream);
  } else {
    diag_kernel<<<1,1,0,stream>>>((float*)d_out, (float)((double)ws_size/1.0e6));
  }
}